// Round 18
// baseline (148.865 us; speedup 1.0000x reference)
//
#include <hip/hip_runtime.h>
#include <hip/hip_bf16.h>

// MultiHeadAttention: x[2,2048,1024] fp32, Wq/Wk/Wv/Wo[1024,1024] fp32
// out = softmax((xWq^T)(xWk^T)^T * 0.125) (xWv^T) Wo^T   per head (H=16, Dh=64)

typedef __attribute__((ext_vector_type(8))) short bf16x8;
typedef __attribute__((ext_vector_type(4))) short bf16x4v;
typedef __attribute__((ext_vector_type(4))) float f32x4;
typedef __attribute__((ext_vector_type(16))) float f32x16;

#define MFMA_16x16x32(a, b, c) __builtin_amdgcn_mfma_f32_16x16x32_bf16((a), (b), (c), 0, 0, 0)
#define MFMA_32x32x16(a, b, c) __builtin_amdgcn_mfma_f32_32x32x16_bf16((a), (b), (c), 0, 0, 0)

static __device__ __forceinline__ void gload_lds16(const void* g, void* l) {
  __builtin_amdgcn_global_load_lds((const __attribute__((address_space(1))) void*)g,
                                   (__attribute__((address_space(3))) void*)l, 16, 0, 0);
}

static __device__ __forceinline__ short f2bf(float f) {
  __hip_bfloat16 h = __float2bfloat16(f);
  return *reinterpret_cast<short*>(&h);
}
static __device__ __forceinline__ float bf2f(short s) {
  unsigned u = ((unsigned)(unsigned short)s) << 16;
  union { unsigned u; float f; } cv; cv.u = u; return cv.f;
}
// packed f32x2 -> bf16x2 (single instruction; no builtin on gfx950)
static __device__ __forceinline__ unsigned cvt_pk_bf16(float lo, float hi) {
  unsigned r;
  asm("v_cvt_pk_bf16_f32 %0, %1, %2" : "=v"(r) : "v"(lo), "v"(hi));
  return r;
}

// ---------- fused cast: x (4M f32) + Wo|Wq|Wk|Wv (4M f32) -> bf16 ----------
__global__ __launch_bounds__(256) void cast_all(const float* __restrict__ x,
                                                const float* __restrict__ wq,
                                                const float* __restrict__ wk,
                                                const float* __restrict__ wv,
                                                const float* __restrict__ wo,
                                                __hip_bfloat16* __restrict__ xb,
                                                __hip_bfloat16* __restrict__ wall) {
  int i = blockIdx.x * 256 + threadIdx.x;  // 0 .. 8*2^18-1 (float4 units)
  const int reg = i >> 18;
  const float* src;
  __hip_bfloat16* dst;
  int di, si;
  if (reg < 4) {
    src = x; di = i; si = i; dst = xb;
  } else {
    src = (reg == 4) ? wo : (reg == 5) ? wq : (reg == 6) ? wk : wv;
    di = i - (4 << 18);
    si = i & 0x3FFFF;
    dst = wall;
  }
  const float4 v = reinterpret_cast<const float4*>(src)[si];
  bf16x4v o;
  o[0] = f2bf(v.x); o[1] = f2bf(v.y); o[2] = f2bf(v.z); o[3] = f2bf(v.w);
  reinterpret_cast<bf16x4v*>(dst)[di] = o;
}

// ---------- C[m,n] = sum_k A[m,k]*B[n,k];  M=4096, K=1024, N = col-stride ----------
// WRITE_VT: V-column blocks of the fused QKV GEMM write V^T via LDS bounce.
// MERGE_A: A operand is the merged attention output, computed on the fly from
//   the two KV-split partials + lsums during A-staging (reg path + ds_write);
//   K-step k0 corresponds exactly to head h = k0/64. Values identical to the
//   old merge_kernel output (same fp32 expression, one bf16 round-trip fewer).
template <int MFRAG, int OUT_F32, int WRITE_VT, int MERGE_A>
__global__ __launch_bounds__(256) void gemm_bt(const __hip_bfloat16* __restrict__ A,
                                               const __hip_bfloat16* __restrict__ B,
                                               void* __restrict__ C, int N, int nbx,
                                               __hip_bfloat16* __restrict__ vt,
                                               const __hip_bfloat16* __restrict__ partb,
                                               const float* __restrict__ stats) {
  __shared__ __align__(16) short As[MFRAG * 32 * 64];
  __shared__ __align__(16) short Bs[128 * 64];
  const int tid = threadIdx.x;
  const int lane = tid & 63, wid = tid >> 6;
  const int l15 = lane & 15, l4 = lane >> 4;
  const int wr = wid >> 1, wc = wid & 1;
  const int m0 = (blockIdx.x / nbx) * (MFRAG * 32);
  const int n0 = (blockIdx.x % nbx) * 128;
  const short* Ag = (const short*)A;
  const short* Bg = (const short*)B;

  f32x4 acc[MFRAG][4] = {};

  for (int k0 = 0; k0 < 1024; k0 += 64) {
#pragma unroll
    for (int it = 0; it < MFRAG; ++it) {
      const int u = (it * 4 + wid) * 64 + lane;
      const int row = u >> 3, col = (u & 7) << 3;
      if constexpr (MERGE_A) {
        // A[t][k0+col..+8] = (part0 + part1) * inv_lsum  (head h = k0>>6)
        const int t = m0 + row;
        const int hh = k0 >> 6;
        const int bq = t >> 11;
        const int qtt = (t & 2047) >> 7;
        const int r128 = t & 127;
        const size_t base = ((size_t)((bq * 16 + hh) * 16 + qtt)) * 2;
        const float l0 = stats[base * 128 + r128];
        const float l1 = stats[(base + 1) * 128 + r128];
        const float inv = 1.0f / (l0 + l1);
        const short* pg = (const short*)partb;
        const bf16x8 a0 = *(const bf16x8*)(pg + base * 8192 + (size_t)r128 * 64 + col);
        const bf16x8 a1 = *(const bf16x8*)(pg + (base + 1) * 8192 + (size_t)r128 * 64 + col);
        bf16x8 w;
#pragma unroll
        for (int e = 0; e < 8; ++e) w[e] = f2bf((bf2f(a0[e]) + bf2f(a1[e])) * inv);
        *(bf16x8*)(As + (size_t)u * 8) = w;
      } else {
        gload_lds16(Ag + (size_t)(m0 + row) * 1024 + k0 + col, As + (size_t)u * 8);
      }
    }
#pragma unroll
    for (int it = 0; it < 4; ++it) {
      const int u = (it * 4 + wid) * 64 + lane;
      const int row = u >> 3, col = (u & 7) << 3;
      gload_lds16(Bg + (size_t)(n0 + row) * 1024 + k0 + col, Bs + (size_t)u * 8);
    }
    __syncthreads();
#pragma unroll
    for (int kc = 0; kc < 2; ++kc) {
      bf16x8 a[MFRAG], b[4];
#pragma unroll
      for (int i = 0; i < MFRAG; ++i)
        a[i] = *(const bf16x8*)(As + (wr * MFRAG * 16 + i * 16 + l15) * 64 + kc * 32 + l4 * 8);
#pragma unroll
      for (int j = 0; j < 4; ++j)
        b[j] = *(const bf16x8*)(Bs + (wc * 64 + j * 16 + l15) * 64 + kc * 32 + l4 * 8);
#pragma unroll
      for (int i = 0; i < MFRAG; ++i)
#pragma unroll
        for (int j = 0; j < 4; ++j)
          acc[i][j] = MFMA_16x16x32(a[i], b[j], acc[i][j]);
    }
    __syncthreads();
  }

  if constexpr (WRITE_VT) {
    if (n0 >= 2048) {
      // 1) each wave parks its 64(vc) x 64(s) sub-tile in a 4096-short LDS
      //    region, s-offset XOR-swizzled by (vc&7)<<3 (bank-conflict-free).
      short* wreg = (wid < 2) ? &As[wid * 4096] : &Bs[(wid - 2) * 4096];
#pragma unroll
      for (int i = 0; i < MFRAG; ++i) {
#pragma unroll
        for (int j = 0; j < 4; ++j) {
          const int vc = j * 16 + l15;
          const int sb = i * 16 + l4 * 4;
          bf16x4v w;
#pragma unroll
          for (int r = 0; r < 4; ++r) w[r] = f2bf(acc[i][j][r]);
          *(bf16x4v*)(wreg + vc * 64 + (sb ^ ((vc & 7) << 3))) = w;
        }
      }
      __syncthreads();
      // 2) all 256 threads drain s-major: 16-lane group -> one vc row,
      //    128B contiguous along s per store instruction.
      const int q = tid >> 6;  // source wave region
      const short* rreg = (q < 2) ? &As[q * 4096] : &Bs[(q - 2) * 4096];
      const int wrq = q >> 1, wcq = q & 1;
      const int srow = m0 + wrq * 64;
      const int bq = srow >> 11, sloc = srow & 2047;
      short* vg = (short*)vt;
#pragma unroll
      for (int it = 0; it < 16; ++it) {
        const int vc = it * 4 + l4;
        const int vcg = n0 - 2048 + wcq * 64 + vc;
        bf16x4v w = *(const bf16x4v*)(rreg + vc * 64 + ((l15 * 4) ^ ((vc & 7) << 3)));
        *(bf16x4v*)(vg + ((size_t)(bq * 1024 + vcg)) * 2048 + sloc + l15 * 4) = w;
      }
      return;
    }
  }

#pragma unroll
  for (int i = 0; i < MFRAG; ++i)
#pragma unroll
    for (int j = 0; j < 4; ++j) {
      const int row0 = m0 + wr * MFRAG * 16 + i * 16 + l4 * 4;
      const int col = n0 + wc * 64 + j * 16 + l15;
#pragma unroll
      for (int r = 0; r < 4; ++r) {
        if (OUT_F32)
          ((float*)C)[(size_t)(row0 + r) * N + col] = acc[i][j][r];
        else
          ((short*)C)[(size_t)(row0 + r) * N + col] = f2bf(acc[i][j][r]);
      }
    }
}

// ---------- flash attention, KV-split x2, swapped 32x32x16, no-max softmax ----------
// (round-17 version, unchanged: counted-vmcnt pipeline + __expf + ones-MFMA)
__global__ __launch_bounds__(256, 4) void attn_kernel(const __hip_bfloat16* __restrict__ QKVp,
                                                      const __hip_bfloat16* __restrict__ Vtp,
                                                      __hip_bfloat16* __restrict__ partb,
                                                      float* __restrict__ stats) {
  __shared__ __align__(16) short Kb[3][64 * 64];
  __shared__ __align__(16) short Vb[2][64 * 64];
  // XCD-chunked bijective swizzle: 1024 blocks, 8 XCDs -> chunks of 128
  int bid = (int)blockIdx.x;
  bid = (bid & 7) * 128 + (bid >> 3);
  const int sg = bid & 1;
  const int qtt = (bid >> 1) & 15;
  const int bh = bid >> 5;  // b*16 + h
  const int h = bh & 15, b = bh >> 4;
  const int tid = threadIdx.x;
  const int lane = tid & 63, wid = tid >> 6;
  const int l31 = lane & 31, l5 = lane >> 5;
  const size_t tokW = (size_t)b * 2048 + qtt * 128 + wid * 32;
  const short* QKV = (const short*)QKVp;
  const short* Kg = QKV + (size_t)b * 2048 * 3072 + 1024 + h * 64;
  const short* Vg = (const short*)Vtp + (size_t)bh * 64 * 2048;
  const int kbase = sg * 16;

  // Q fragments (B-operand of S^T mfma), pre-scaled by 0.125 (e-domain)
  bf16x8 qf[4];
#pragma unroll
  for (int kc = 0; kc < 4; ++kc) {
    bf16x8 raw = *(const bf16x8*)(QKV + (tokW + l31) * 3072 + h * 64 + kc * 16 + l5 * 8);
#pragma unroll
    for (int e = 0; e < 8; ++e) qf[kc][e] = f2bf(bf2f(raw[e]) * 0.125f);
  }

  // all-ones A-fragment for the lsum MFMA (bf16 1.0 = 0x3F80)
  bf16x8 onesf;
#pragma unroll
  for (int e = 0; e < 8; ++e) onesf[e] = (short)0x3F80;

  auto stageK = [&](int slot, int kt) {
    const int ktg = kbase + kt;
#pragma unroll
    for (int it = 0; it < 2; ++it) {
      const int flat = it * 256 + tid;
      const int r = flat >> 3;
      const int c = (flat & 7) ^ (r & 7);
      gload_lds16(Kg + (size_t)(ktg * 64 + r) * 3072 + c * 8, &Kb[slot][(size_t)flat * 8]);
    }
  };
  auto stageV = [&](int slot, int kt) {
    const int ktg = kbase + kt;
#pragma unroll
    for (int it = 0; it < 2; ++it) {
      const int flat = it * 256 + tid;
      const int r = flat >> 3;
      const int c = (flat & 7) ^ (r & 7);
      gload_lds16(Vg + (size_t)r * 2048 + ktg * 64 + c * 8, &Vb[slot][(size_t)flat * 8]);
    }
  };

  // prologue: FIFO = [K0,K0, V0,V0, K1,K1]; vmcnt(4) -> K0 landed.
  stageK(0, 0);
  stageV(0, 0);
  stageK(1, 1);
  asm volatile("s_waitcnt vmcnt(4)" ::: "memory");
  __builtin_amdgcn_s_barrier();
  __builtin_amdgcn_sched_barrier(0);

  f32x16 o0 = {}, o1 = {}, ol = {};

  for (int kt = 0; kt < 16; ++kt) {
    const int ks3 = kt % 3;       // K read slot
    const int vs = kt & 1;        // V read slot
    if (kt < 14) stageK((kt + 2) % 3, kt + 2);
    if (kt < 15) stageV((kt + 1) & 1, kt + 1);

    // ---- S^T[k][q] (e-domain scores), K from Kb[ks3] ----
    f32x16 s0 = {}, s1 = {};
    __builtin_amdgcn_s_setprio(1);
#pragma unroll
    for (int kc = 0; kc < 4; ++kc) {
      const int u0 = (kc * 2 + l5) ^ (l31 & 7);
      const bf16x8 kf0 = *(const bf16x8*)(&Kb[ks3][l31 * 64 + u0 * 8]);
      s0 = MFMA_32x32x16(kf0, qf[kc], s0);
      const int row1 = 32 + l31;
      const int u1 = (kc * 2 + l5) ^ (row1 & 7);
      const bf16x8 kf1 = *(const bf16x8*)(&Kb[ks3][row1 * 64 + u1 * 8]);
      s1 = MFMA_32x32x16(kf1, qf[kc], s1);
    }
    __builtin_amdgcn_s_setprio(0);

    // ---- P = exp(S) via __expf (native v_exp_f32), packed to bf16 pairs ----
    unsigned pkd0[4][2], pkd1[4][2];  // [group g][dword]: rows 8g+4*l5 + {0,1},{2,3}
#pragma unroll
    for (int g = 0; g < 4; ++g) {
      pkd0[g][0] = cvt_pk_bf16(__expf(s0[4 * g + 0]), __expf(s0[4 * g + 1]));
      pkd0[g][1] = cvt_pk_bf16(__expf(s0[4 * g + 2]), __expf(s0[4 * g + 3]));
      pkd1[g][0] = cvt_pk_bf16(__expf(s1[4 * g + 0]), __expf(s1[4 * g + 1]));
      pkd1[g][1] = cvt_pk_bf16(__expf(s1[4 * g + 2]), __expf(s1[4 * g + 3]));
    }

    // ---- late V wait: drain exactly through V(kt) ----
    if (kt < 14)      { asm volatile("s_waitcnt vmcnt(4)" ::: "memory"); }
    else if (kt < 15) { asm volatile("s_waitcnt vmcnt(2)" ::: "memory"); }
    else              { asm volatile("s_waitcnt vmcnt(0)" ::: "memory"); }
    __builtin_amdgcn_sched_barrier(0);

    // ---- O^T += V^T . P^T ;  ol += ones . P^T (lsum on the MFMA pipe) ----
    __builtin_amdgcn_s_setprio(1);
#pragma unroll
    for (int ks = 0; ks < 4; ++ks) {
      const int gA = (2 * ks) & 3, gB = (2 * ks + 1) & 3;
      unsigned a0, a1, b0, b1;
      if (ks < 2) { a0 = pkd0[gA][0]; a1 = pkd0[gA][1]; b0 = pkd0[gB][0]; b1 = pkd0[gB][1]; }
      else        { a0 = pkd1[gA][0]; a1 = pkd1[gA][1]; b0 = pkd1[gB][0]; b1 = pkd1[gB][1]; }
      union { unsigned d[4]; bf16x8 v; } pf;
#if __has_builtin(__builtin_amdgcn_permlane32_swap)
      {
        auto r0 = __builtin_amdgcn_permlane32_swap(a0, b0, false, false);
        auto r1 = __builtin_amdgcn_permlane32_swap(a1, b1, false, false);
        pf.d[0] = r0[0]; pf.d[1] = r1[0]; pf.d[2] = r0[1]; pf.d[3] = r1[1];
      }
#else
      {
        const unsigned long long A = (unsigned long long)a0 | ((unsigned long long)a1 << 32);
        const unsigned long long B = (unsigned long long)b0 | ((unsigned long long)b1 << 32);
        const unsigned long long own = l5 ? B : A;
        const unsigned long long send = l5 ? A : B;
        const unsigned long long recv = __shfl_xor(send, 32);
        const unsigned long long w0 = l5 ? recv : own;
        const unsigned long long w1 = l5 ? own : recv;
        pf.d[0] = (unsigned)w0; pf.d[1] = (unsigned)(w0 >> 32);
        pf.d[2] = (unsigned)w1; pf.d[3] = (unsigned)(w1 >> 32);
      }
#endif
      ol = MFMA_32x32x16(onesf, pf.v, ol);
      {
        const int u = (ks * 2 + l5) ^ (l31 & 7);
        const bf16x8 vf = *(const bf16x8*)(&Vb[vs][l31 * 64 + u * 8]);
        o0 = MFMA_32x32x16(vf, pf.v, o0);
      }
      {
        const int row = 32 + l31;
        const int u = (ks * 2 + l5) ^ (row & 7);
        const bf16x8 vf = *(const bf16x8*)(&Vb[vs][row * 64 + u * 8]);
        o1 = MFMA_32x32x16(vf, pf.v, o1);
      }
    }
    __builtin_amdgcn_s_setprio(0);

    if (kt < 15) {
      __builtin_amdgcn_s_barrier();
      __builtin_amdgcn_sched_barrier(0);
    }
  }

  // ---- epilogue: store unnormalized partial O (bf16) + row-sum ----
  const float lsum = ol[0];  // ol[r] = lsum[q=l31] for all r; covers both halves
  const size_t pbase = ((size_t)(bh * 16 + qtt) * 2 + sg) * 8192;
  const int ql = wid * 32 + l31;
  short* pg = (short*)partb;
#pragma unroll
  for (int mt = 0; mt < 2; ++mt) {
    const f32x16& o = mt ? o1 : o0;
#pragma unroll
    for (int rg = 0; rg < 4; ++rg) {
      const int d0 = 32 * mt + 8 * rg + 4 * l5;
      bf16x4v w;
#pragma unroll
      for (int el = 0; el < 4; ++el) w[el] = f2bf(o[4 * rg + el]);
      *(bf16x4v*)(pg + pbase + (size_t)ql * 64 + d0) = w;
    }
  }
  if (l5 == 0) {
    const size_t sb = ((size_t)(bh * 16 + qtt) * 2 + sg) * 128;
    stats[sb + ql] = lsum;
  }
}

extern "C" void kernel_launch(void* const* d_in, const int* in_sizes, int n_in,
                              void* d_out, int out_size, void* d_ws, size_t ws_size,
                              hipStream_t stream) {
  const float* x = (const float*)d_in[0];
  const float* Wq = (const float*)d_in[1];
  const float* Wk = (const float*)d_in[2];
  const float* Wv = (const float*)d_in[3];
  const float* Wo = (const float*)d_in[4];
  float* out = (float*)d_out;

  __hip_bfloat16* ws = (__hip_bfloat16*)d_ws;
  const size_t MT = (size_t)4096 * 1024;
  const size_t WT = (size_t)1024 * 1024;
  __hip_bfloat16* xb = ws;             // x bf16 (dead after QKV gemm)
  __hip_bfloat16* wall = ws + MT;      // [Wo][Wq][Wk][Wv] bf16
  __hip_bfloat16* wob = wall;
  __hip_bfloat16* wqkv = wall + WT;    // Wq|Wk|Wv contiguous (3072 rows)
  __hip_bfloat16* qkvb = wall + 4 * WT;              // [4096, 3072] (V third unused)
  __hip_bfloat16* vtb = qkvb + (size_t)4096 * 3072;  // [2,16,64,2048] V^T
  __hip_bfloat16* partb = vtb + MT;                  // partial O, 8M bf16 (16MB)
  float* stats = (float*)wqkv;         // 512KB, overlays dead Wq-bf16 during attn

  cast_all<<<8192, 256, 0, stream>>>(x, Wq, Wk, Wv, Wo, xb, wall);

  // fused QKV projection: [4096,1024] x [3072,1024]^T -> Q|K into qkvb,
  // V written directly transposed (coalesced via LDS bounce) into vtb.
  gemm_bt<4, 0, 1, 0><<<768, 256, 0, stream>>>(xb, wqkv, qkvb, 3072, 24, vtb,
                                               nullptr, nullptr);

  attn_kernel<<<1024, 256, 0, stream>>>(qkvb, vtb, partb, stats);

  // output projection with fused KV-split merge: A = (part0+part1)*inv_lsum
  // computed during A-staging (merge kernel eliminated).
  gemm_bt<2, 1, 0, 1><<<512, 256, 0, stream>>>(nullptr, wob, out, 1024, 8, nullptr,
                                               partb, stats);
}

// Round 19
// 138.209 us; speedup vs baseline: 1.0771x; 1.0771x over previous
//
#include <hip/hip_runtime.h>
#include <hip/hip_bf16.h>

// MultiHeadAttention: x[2,2048,1024] fp32, Wq/Wk/Wv/Wo[1024,1024] fp32
// out = softmax((xWq^T)(xWk^T)^T * 0.125) (xWv^T) Wo^T   per head (H=16, Dh=64)

typedef __attribute__((ext_vector_type(8))) short bf16x8;
typedef __attribute__((ext_vector_type(4))) short bf16x4v;
typedef __attribute__((ext_vector_type(4))) float f32x4;
typedef __attribute__((ext_vector_type(16))) float f32x16;

#define MFMA_16x16x32(a, b, c) __builtin_amdgcn_mfma_f32_16x16x32_bf16((a), (b), (c), 0, 0, 0)
#define MFMA_32x32x16(a, b, c) __builtin_amdgcn_mfma_f32_32x32x16_bf16((a), (b), (c), 0, 0, 0)

static __device__ __forceinline__ void gload_lds16(const void* g, void* l) {
  __builtin_amdgcn_global_load_lds((const __attribute__((address_space(1))) void*)g,
                                   (__attribute__((address_space(3))) void*)l, 16, 0, 0);
}

static __device__ __forceinline__ short f2bf(float f) {
  __hip_bfloat16 h = __float2bfloat16(f);
  return *reinterpret_cast<short*>(&h);
}
static __device__ __forceinline__ float bf2f(short s) {
  unsigned u = ((unsigned)(unsigned short)s) << 16;
  union { unsigned u; float f; } cv; cv.u = u; return cv.f;
}
// packed f32x2 -> bf16x2 (single instruction; no builtin on gfx950)
static __device__ __forceinline__ unsigned cvt_pk_bf16(float lo, float hi) {
  unsigned r;
  asm("v_cvt_pk_bf16_f32 %0, %1, %2" : "=v"(r) : "v"(lo), "v"(hi));
  return r;
}

// ---------- fused cast: x (4M f32) + Wo|Wq|Wk|Wv (4M f32) -> bf16 ----------
__global__ __launch_bounds__(256) void cast_all(const float* __restrict__ x,
                                                const float* __restrict__ wq,
                                                const float* __restrict__ wk,
                                                const float* __restrict__ wv,
                                                const float* __restrict__ wo,
                                                __hip_bfloat16* __restrict__ xb,
                                                __hip_bfloat16* __restrict__ wall) {
  int i = blockIdx.x * 256 + threadIdx.x;  // 0 .. 8*2^18-1 (float4 units)
  const int reg = i >> 18;
  const float* src;
  __hip_bfloat16* dst;
  int di, si;
  if (reg < 4) {
    src = x; di = i; si = i; dst = xb;
  } else {
    src = (reg == 4) ? wo : (reg == 5) ? wq : (reg == 6) ? wk : wv;
    di = i - (4 << 18);
    si = i & 0x3FFFF;
    dst = wall;
  }
  const float4 v = reinterpret_cast<const float4*>(src)[si];
  bf16x4v o;
  o[0] = f2bf(v.x); o[1] = f2bf(v.y); o[2] = f2bf(v.z); o[3] = f2bf(v.w);
  reinterpret_cast<bf16x4v*>(dst)[di] = o;
}

// ---------- C[m,n] = sum_k A[m,k]*B[n,k];  M=4096, K=1024, N = col-stride ----------
// Block tile (MFRAG*32) x 128; 4 waves as 2x2; wave tile (MFRAG*16) x 64.
// WRITE_VT: V-column blocks (n0>=2048) of the fused QKV GEMM write V^T
// [b,h,d,s] via a generalized LDS bounce (coalesced s-major stores).
template <int MFRAG, int OUT_F32, int WRITE_VT>
__global__ __launch_bounds__(256) void gemm_bt(const __hip_bfloat16* __restrict__ A,
                                               const __hip_bfloat16* __restrict__ B,
                                               void* __restrict__ C, int N, int nbx,
                                               __hip_bfloat16* __restrict__ vt) {
  __shared__ __align__(16) short As[MFRAG * 32 * 64];
  __shared__ __align__(16) short Bs[128 * 64];
  const int tid = threadIdx.x;
  const int lane = tid & 63, wid = tid >> 6;
  const int l15 = lane & 15, l4 = lane >> 4;
  const int wr = wid >> 1, wc = wid & 1;
  const int m0 = (blockIdx.x / nbx) * (MFRAG * 32);
  const int n0 = (blockIdx.x % nbx) * 128;
  const short* Ag = (const short*)A;
  const short* Bg = (const short*)B;

  f32x4 acc[MFRAG][4] = {};

  for (int k0 = 0; k0 < 1024; k0 += 64) {
#pragma unroll
    for (int it = 0; it < MFRAG; ++it) {
      const int u = (it * 4 + wid) * 64 + lane;
      const int row = u >> 3, col = (u & 7) << 3;
      gload_lds16(Ag + (size_t)(m0 + row) * 1024 + k0 + col, As + (size_t)u * 8);
    }
#pragma unroll
    for (int it = 0; it < 4; ++it) {
      const int u = (it * 4 + wid) * 64 + lane;
      const int row = u >> 3, col = (u & 7) << 3;
      gload_lds16(Bg + (size_t)(n0 + row) * 1024 + k0 + col, Bs + (size_t)u * 8);
    }
    __syncthreads();
#pragma unroll
    for (int kc = 0; kc < 2; ++kc) {
      bf16x8 a[MFRAG], b[4];
#pragma unroll
      for (int i = 0; i < MFRAG; ++i)
        a[i] = *(const bf16x8*)(As + (wr * MFRAG * 16 + i * 16 + l15) * 64 + kc * 32 + l4 * 8);
#pragma unroll
      for (int j = 0; j < 4; ++j)
        b[j] = *(const bf16x8*)(Bs + (wc * 64 + j * 16 + l15) * 64 + kc * 32 + l4 * 8);
#pragma unroll
      for (int i = 0; i < MFRAG; ++i)
#pragma unroll
        for (int j = 0; j < 4; ++j)
          acc[i][j] = MFMA_16x16x32(a[i], b[j], acc[i][j]);
    }
    __syncthreads();
  }

  if constexpr (WRITE_VT) {
    if (n0 >= 2048) {
      // SM = s-rows per wave sub-tile. Park offset vc*SM + (sb ^ swz):
      // swz = (vc & (SM/8-1))<<3 stays in [0,SM) and only touches bits>=3,
      // so 4-short blocks remain contiguous (s4 is 4-aligned).
      constexpr int SM = MFRAG * 16;
      constexpr int SWM = SM / 8 - 1;
      short* wreg = (wid < 2) ? &As[wid * 64 * SM] : &Bs[(wid - 2) * 64 * SM];
#pragma unroll
      for (int i = 0; i < MFRAG; ++i) {
#pragma unroll
        for (int j = 0; j < 4; ++j) {
          const int vc = j * 16 + l15;
          const int sb = i * 16 + l4 * 4;
          bf16x4v w;
#pragma unroll
          for (int r = 0; r < 4; ++r) w[r] = f2bf(acc[i][j][r]);
          *(bf16x4v*)(wreg + vc * SM + (sb ^ ((vc & SWM) << 3))) = w;
        }
      }
      __syncthreads();
      // drain: 64-lane group q empties wave q's region, SM/4 lanes per vc row
      // -> SM*2B contiguous along s per row (64-128B stores).
      constexpr int LPR = SM / 4;        // lanes per vc row
      constexpr int RPI = 64 / LPR;      // vc rows per iteration
      const int q = tid >> 6;
      const short* rreg = (q < 2) ? &As[q * 64 * SM] : &Bs[(q - 2) * 64 * SM];
      const int wrq = q >> 1, wcq = q & 1;
      const int srow = m0 + wrq * SM;
      const int bq = srow >> 11, sloc = srow & 2047;
      short* vg = (short*)vt;
#pragma unroll
      for (int it = 0; it < 64 / RPI; ++it) {
        const int vc = it * RPI + lane / LPR;
        const int s4 = (lane % LPR) * 4;
        const int vcg = n0 - 2048 + wcq * 64 + vc;
        bf16x4v w = *(const bf16x4v*)(rreg + vc * SM + (s4 ^ ((vc & SWM) << 3)));
        *(bf16x4v*)(vg + ((size_t)(bq * 1024 + vcg)) * 2048 + sloc + s4) = w;
      }
      return;
    }
  }

#pragma unroll
  for (int i = 0; i < MFRAG; ++i)
#pragma unroll
    for (int j = 0; j < 4; ++j) {
      const int row0 = m0 + wr * MFRAG * 16 + i * 16 + l4 * 4;
      const int col = n0 + wc * 64 + j * 16 + l15;
#pragma unroll
      for (int r = 0; r < 4; ++r) {
        if (OUT_F32)
          ((float*)C)[(size_t)(row0 + r) * N + col] = acc[i][j][r];
        else
          ((short*)C)[(size_t)(row0 + r) * N + col] = f2bf(acc[i][j][r]);
      }
    }
}

// ---------- flash attention, KV-split x2, swapped 32x32x16, no-max softmax ----------
// (round-17 version, unchanged: counted-vmcnt pipeline + __expf + ones-MFMA)
__global__ __launch_bounds__(256, 4) void attn_kernel(const __hip_bfloat16* __restrict__ QKVp,
                                                      const __hip_bfloat16* __restrict__ Vtp,
                                                      __hip_bfloat16* __restrict__ partb,
                                                      float* __restrict__ stats) {
  __shared__ __align__(16) short Kb[3][64 * 64];
  __shared__ __align__(16) short Vb[2][64 * 64];
  // XCD-chunked bijective swizzle: 1024 blocks, 8 XCDs -> chunks of 128
  int bid = (int)blockIdx.x;
  bid = (bid & 7) * 128 + (bid >> 3);
  const int sg = bid & 1;
  const int qtt = (bid >> 1) & 15;
  const int bh = bid >> 5;  // b*16 + h
  const int h = bh & 15, b = bh >> 4;
  const int tid = threadIdx.x;
  const int lane = tid & 63, wid = tid >> 6;
  const int l31 = lane & 31, l5 = lane >> 5;
  const size_t tokW = (size_t)b * 2048 + qtt * 128 + wid * 32;
  const short* QKV = (const short*)QKVp;
  const short* Kg = QKV + (size_t)b * 2048 * 3072 + 1024 + h * 64;
  const short* Vg = (const short*)Vtp + (size_t)bh * 64 * 2048;
  const int kbase = sg * 16;

  // Q fragments (B-operand of S^T mfma), pre-scaled by 0.125 (e-domain)
  bf16x8 qf[4];
#pragma unroll
  for (int kc = 0; kc < 4; ++kc) {
    bf16x8 raw = *(const bf16x8*)(QKV + (tokW + l31) * 3072 + h * 64 + kc * 16 + l5 * 8);
#pragma unroll
    for (int e = 0; e < 8; ++e) qf[kc][e] = f2bf(bf2f(raw[e]) * 0.125f);
  }

  // all-ones A-fragment for the lsum MFMA (bf16 1.0 = 0x3F80)
  bf16x8 onesf;
#pragma unroll
  for (int e = 0; e < 8; ++e) onesf[e] = (short)0x3F80;

  auto stageK = [&](int slot, int kt) {
    const int ktg = kbase + kt;
#pragma unroll
    for (int it = 0; it < 2; ++it) {
      const int flat = it * 256 + tid;
      const int r = flat >> 3;
      const int c = (flat & 7) ^ (r & 7);
      gload_lds16(Kg + (size_t)(ktg * 64 + r) * 3072 + c * 8, &Kb[slot][(size_t)flat * 8]);
    }
  };
  auto stageV = [&](int slot, int kt) {
    const int ktg = kbase + kt;
#pragma unroll
    for (int it = 0; it < 2; ++it) {
      const int flat = it * 256 + tid;
      const int r = flat >> 3;
      const int c = (flat & 7) ^ (r & 7);
      gload_lds16(Vg + (size_t)r * 2048 + ktg * 64 + c * 8, &Vb[slot][(size_t)flat * 8]);
    }
  };

  // prologue: FIFO = [K0,K0, V0,V0, K1,K1]; vmcnt(4) -> K0 landed.
  stageK(0, 0);
  stageV(0, 0);
  stageK(1, 1);
  asm volatile("s_waitcnt vmcnt(4)" ::: "memory");
  __builtin_amdgcn_s_barrier();
  __builtin_amdgcn_sched_barrier(0);

  f32x16 o0 = {}, o1 = {}, ol = {};

  for (int kt = 0; kt < 16; ++kt) {
    const int ks3 = kt % 3;       // K read slot
    const int vs = kt & 1;        // V read slot
    if (kt < 14) stageK((kt + 2) % 3, kt + 2);
    if (kt < 15) stageV((kt + 1) & 1, kt + 1);

    // ---- S^T[k][q] (e-domain scores), K from Kb[ks3] ----
    f32x16 s0 = {}, s1 = {};
    __builtin_amdgcn_s_setprio(1);
#pragma unroll
    for (int kc = 0; kc < 4; ++kc) {
      const int u0 = (kc * 2 + l5) ^ (l31 & 7);
      const bf16x8 kf0 = *(const bf16x8*)(&Kb[ks3][l31 * 64 + u0 * 8]);
      s0 = MFMA_32x32x16(kf0, qf[kc], s0);
      const int row1 = 32 + l31;
      const int u1 = (kc * 2 + l5) ^ (row1 & 7);
      const bf16x8 kf1 = *(const bf16x8*)(&Kb[ks3][row1 * 64 + u1 * 8]);
      s1 = MFMA_32x32x16(kf1, qf[kc], s1);
    }
    __builtin_amdgcn_s_setprio(0);

    // ---- P = exp(S) via __expf (native v_exp_f32), packed to bf16 pairs ----
    unsigned pkd0[4][2], pkd1[4][2];  // [group g][dword]: rows 8g+4*l5 + {0,1},{2,3}
#pragma unroll
    for (int g = 0; g < 4; ++g) {
      pkd0[g][0] = cvt_pk_bf16(__expf(s0[4 * g + 0]), __expf(s0[4 * g + 1]));
      pkd0[g][1] = cvt_pk_bf16(__expf(s0[4 * g + 2]), __expf(s0[4 * g + 3]));
      pkd1[g][0] = cvt_pk_bf16(__expf(s1[4 * g + 0]), __expf(s1[4 * g + 1]));
      pkd1[g][1] = cvt_pk_bf16(__expf(s1[4 * g + 2]), __expf(s1[4 * g + 3]));
    }

    // ---- late V wait: drain exactly through V(kt) ----
    if (kt < 14)      { asm volatile("s_waitcnt vmcnt(4)" ::: "memory"); }
    else if (kt < 15) { asm volatile("s_waitcnt vmcnt(2)" ::: "memory"); }
    else              { asm volatile("s_waitcnt vmcnt(0)" ::: "memory"); }
    __builtin_amdgcn_sched_barrier(0);

    // ---- O^T += V^T . P^T ;  ol += ones . P^T (lsum on the MFMA pipe) ----
    __builtin_amdgcn_s_setprio(1);
#pragma unroll
    for (int ks = 0; ks < 4; ++ks) {
      const int gA = (2 * ks) & 3, gB = (2 * ks + 1) & 3;
      unsigned a0, a1, b0, b1;
      if (ks < 2) { a0 = pkd0[gA][0]; a1 = pkd0[gA][1]; b0 = pkd0[gB][0]; b1 = pkd0[gB][1]; }
      else        { a0 = pkd1[gA][0]; a1 = pkd1[gA][1]; b0 = pkd1[gB][0]; b1 = pkd1[gB][1]; }
      union { unsigned d[4]; bf16x8 v; } pf;
#if __has_builtin(__builtin_amdgcn_permlane32_swap)
      {
        auto r0 = __builtin_amdgcn_permlane32_swap(a0, b0, false, false);
        auto r1 = __builtin_amdgcn_permlane32_swap(a1, b1, false, false);
        pf.d[0] = r0[0]; pf.d[1] = r1[0]; pf.d[2] = r0[1]; pf.d[3] = r1[1];
      }
#else
      {
        const unsigned long long A = (unsigned long long)a0 | ((unsigned long long)a1 << 32);
        const unsigned long long B = (unsigned long long)b0 | ((unsigned long long)b1 << 32);
        const unsigned long long own = l5 ? B : A;
        const unsigned long long send = l5 ? A : B;
        const unsigned long long recv = __shfl_xor(send, 32);
        const unsigned long long w0 = l5 ? recv : own;
        const unsigned long long w1 = l5 ? own : recv;
        pf.d[0] = (unsigned)w0; pf.d[1] = (unsigned)(w0 >> 32);
        pf.d[2] = (unsigned)w1; pf.d[3] = (unsigned)(w1 >> 32);
      }
#endif
      ol = MFMA_32x32x16(onesf, pf.v, ol);
      {
        const int u = (ks * 2 + l5) ^ (l31 & 7);
        const bf16x8 vf = *(const bf16x8*)(&Vb[vs][l31 * 64 + u * 8]);
        o0 = MFMA_32x32x16(vf, pf.v, o0);
      }
      {
        const int row = 32 + l31;
        const int u = (ks * 2 + l5) ^ (row & 7);
        const bf16x8 vf = *(const bf16x8*)(&Vb[vs][row * 64 + u * 8]);
        o1 = MFMA_32x32x16(vf, pf.v, o1);
      }
    }
    __builtin_amdgcn_s_setprio(0);

    if (kt < 15) {
      __builtin_amdgcn_s_barrier();
      __builtin_amdgcn_sched_barrier(0);
    }
  }

  // ---- epilogue: store unnormalized partial O (bf16) + row-sum ----
  const float lsum = ol[0];  // ol[r] = lsum[q=l31] for all r; covers both halves
  const size_t pbase = ((size_t)(bh * 16 + qtt) * 2 + sg) * 8192;
  const int ql = wid * 32 + l31;
  short* pg = (short*)partb;
#pragma unroll
  for (int mt = 0; mt < 2; ++mt) {
    const f32x16& o = mt ? o1 : o0;
#pragma unroll
    for (int rg = 0; rg < 4; ++rg) {
      const int d0 = 32 * mt + 8 * rg + 4 * l5;
      bf16x4v w;
#pragma unroll
      for (int el = 0; el < 4; ++el) w[el] = f2bf(o[4 * rg + el]);
      *(bf16x4v*)(pg + pbase + (size_t)ql * 64 + d0) = w;
    }
  }
  if (l5 == 0) {
    const size_t sb = ((size_t)(bh * 16 + qtt) * 2 + sg) * 128;
    stats[sb + ql] = lsum;
  }
}

// ---------- merge the two KV-splits -> final O (bf16) ----------
__global__ __launch_bounds__(256) void merge_kernel(const __hip_bfloat16* __restrict__ partb,
                                                    const float* __restrict__ stats,
                                                    __hip_bfloat16* __restrict__ O) {
  const int bid = blockIdx.x;
  const int qtt = bid & 15, bh = bid >> 4;
  const int h = bh & 15, b = bh >> 4;
  const int tid = threadIdx.x;
  const int r = tid >> 1, dh = (tid & 1) * 32;
  const size_t base = (size_t)(bh * 16 + qtt) * 2;
  const size_t p0 = base * 8192, p1 = p0 + 8192;
  const float l0 = stats[base * 128 + r], l1 = stats[base * 128 + 128 + r];
  const float inv = 1.0f / (l0 + l1);
  const short* pg = (const short*)partb;
  short* Og = (short*)O;
  const size_t orow = ((size_t)b * 2048 + qtt * 128 + r) * 1024 + h * 64 + dh;
#pragma unroll
  for (int j = 0; j < 8; ++j) {
    bf16x4v a = *(const bf16x4v*)(pg + p0 + (size_t)r * 64 + dh + 4 * j);
    bf16x4v c = *(const bf16x4v*)(pg + p1 + (size_t)r * 64 + dh + 4 * j);
    bf16x4v o;
#pragma unroll
    for (int el = 0; el < 4; ++el) o[el] = f2bf((bf2f(a[el]) + bf2f(c[el])) * inv);
    *(bf16x4v*)(Og + orow + 4 * j) = o;
  }
}

extern "C" void kernel_launch(void* const* d_in, const int* in_sizes, int n_in,
                              void* d_out, int out_size, void* d_ws, size_t ws_size,
                              hipStream_t stream) {
  const float* x = (const float*)d_in[0];
  const float* Wq = (const float*)d_in[1];
  const float* Wk = (const float*)d_in[2];
  const float* Wv = (const float*)d_in[3];
  const float* Wo = (const float*)d_in[4];
  float* out = (float*)d_out;

  __hip_bfloat16* ws = (__hip_bfloat16*)d_ws;
  const size_t MT = (size_t)4096 * 1024;
  const size_t WT = (size_t)1024 * 1024;
  __hip_bfloat16* xb = ws;             // x bf16 (dead after QKV gemm)
  __hip_bfloat16* wall = ws + MT;      // [Wo][Wq][Wk][Wv] bf16
  __hip_bfloat16* wob = wall;
  __hip_bfloat16* wqkv = wall + WT;    // Wq|Wk|Wv contiguous (3072 rows)
  __hip_bfloat16* qkvb = wall + 4 * WT;              // [4096, 3072] (V third unused)
  __hip_bfloat16* vtb = qkvb + (size_t)4096 * 3072;  // [2,16,64,2048]; later final O
  __hip_bfloat16* partb = vtb + MT;                  // partial O, 8M bf16 (16MB)
  float* stats = (float*)wqkv;         // 512KB, overlays dead Wq-bf16 during attn

  cast_all<<<8192, 256, 0, stream>>>(x, Wq, Wk, Wv, Wo, xb, wall);

  // fused QKV projection, 64x128 tiles (1536 blocks = 6/CU): Q|K into qkvb,
  // V written directly transposed (coalesced via LDS bounce) into vtb.
  gemm_bt<2, 0, 1><<<1536, 256, 0, stream>>>(xb, wqkv, qkvb, 3072, 24, vtb);

  attn_kernel<<<1024, 256, 0, stream>>>(qkvb, vtb, partb, stats);

  merge_kernel<<<512, 256, 0, stream>>>(partb, stats, vtb);  // final O -> vtb region

  // output projection, 32x128 tiles (1024 blocks = 4/CU)
  gemm_bt<1, 1, 0><<<1024, 256, 0, stream>>>(vtb, wob, out, 1024, 8, nullptr);
}

// Round 20
// 119.088 us; speedup vs baseline: 1.2500x; 1.1606x over previous
//
#include <hip/hip_runtime.h>
#include <hip/hip_bf16.h>

// MultiHeadAttention: x[2,2048,1024] fp32, Wq/Wk/Wv/Wo[1024,1024] fp32
// out = softmax((xWq^T)(xWk^T)^T * 0.125) (xWv^T) Wo^T   per head (H=16, Dh=64)

typedef __attribute__((ext_vector_type(8))) short bf16x8;
typedef __attribute__((ext_vector_type(4))) short bf16x4v;
typedef __attribute__((ext_vector_type(4))) float f32x4;
typedef __attribute__((ext_vector_type(16))) float f32x16;

#define MFMA_16x16x32(a, b, c) __builtin_amdgcn_mfma_f32_16x16x32_bf16((a), (b), (c), 0, 0, 0)
#define MFMA_32x32x16(a, b, c) __builtin_amdgcn_mfma_f32_32x32x16_bf16((a), (b), (c), 0, 0, 0)

static __device__ __forceinline__ void gload_lds16(const void* g, void* l) {
  __builtin_amdgcn_global_load_lds((const __attribute__((address_space(1))) void*)g,
                                   (__attribute__((address_space(3))) void*)l, 16, 0, 0);
}

static __device__ __forceinline__ short f2bf(float f) {
  __hip_bfloat16 h = __float2bfloat16(f);
  return *reinterpret_cast<short*>(&h);
}
static __device__ __forceinline__ float bf2f(short s) {
  unsigned u = ((unsigned)(unsigned short)s) << 16;
  union { unsigned u; float f; } cv; cv.u = u; return cv.f;
}
// packed f32x2 -> bf16x2 (single instruction; no builtin on gfx950)
static __device__ __forceinline__ unsigned cvt_pk_bf16(float lo, float hi) {
  unsigned r;
  asm("v_cvt_pk_bf16_f32 %0, %1, %2" : "=v"(r) : "v"(lo), "v"(hi));
  return r;
}

// ---------- fused cast: x (4M f32) + Wo|Wq|Wk|Wv (4M f32) -> bf16 ----------
__global__ __launch_bounds__(256) void cast_all(const float* __restrict__ x,
                                                const float* __restrict__ wq,
                                                const float* __restrict__ wk,
                                                const float* __restrict__ wv,
                                                const float* __restrict__ wo,
                                                __hip_bfloat16* __restrict__ xb,
                                                __hip_bfloat16* __restrict__ wall) {
  int i = blockIdx.x * 256 + threadIdx.x;  // 0 .. 8*2^18-1 (float4 units)
  const int reg = i >> 18;
  const float* src;
  __hip_bfloat16* dst;
  int di, si;
  if (reg < 4) {
    src = x; di = i; si = i; dst = xb;
  } else {
    src = (reg == 4) ? wo : (reg == 5) ? wq : (reg == 6) ? wk : wv;
    di = i - (4 << 18);
    si = i & 0x3FFFF;
    dst = wall;
  }
  const float4 v = reinterpret_cast<const float4*>(src)[si];
  bf16x4v o;
  o[0] = f2bf(v.x); o[1] = f2bf(v.y); o[2] = f2bf(v.z); o[3] = f2bf(v.w);
  reinterpret_cast<bf16x4v*>(dst)[di] = o;
}

// ---------- C[m,n] = sum_k A[m,k]*B[n,k];  M=4096, K=1024, N = col-stride ----------
// Block tile (MFRAG*32) x 128; 4 waves as 2x2; wave tile (MFRAG*16) x 64.
// LDS tiles are T2 XOR-swizzled: stage uses linear LDS dest + inverse-swizzled
// GLOBAL source (16B unit cu ^= row&7); fragment reads use unit ^ (l15&7).
// -> ds_read_b128 is bank-conflict-free (8 distinct units x 4 banks, 2-way).
// WRITE_VT: V-column blocks (n0>=2048) of the fused QKV GEMM write V^T
// [b,h,d,s] via a generalized LDS bounce (coalesced s-major stores).
template <int MFRAG, int OUT_F32, int WRITE_VT>
__global__ __launch_bounds__(256) void gemm_bt(const __hip_bfloat16* __restrict__ A,
                                               const __hip_bfloat16* __restrict__ B,
                                               void* __restrict__ C, int N, int nbx,
                                               __hip_bfloat16* __restrict__ vt) {
  __shared__ __align__(16) short As[MFRAG * 32 * 64];
  __shared__ __align__(16) short Bs[128 * 64];
  const int tid = threadIdx.x;
  const int lane = tid & 63, wid = tid >> 6;
  const int l15 = lane & 15, l4 = lane >> 4;
  const int l7 = l15 & 7;
  const int wr = wid >> 1, wc = wid & 1;
  const int m0 = (blockIdx.x / nbx) * (MFRAG * 32);
  const int n0 = (blockIdx.x % nbx) * 128;
  const short* Ag = (const short*)A;
  const short* Bg = (const short*)B;

  f32x4 acc[MFRAG][4] = {};

  for (int k0 = 0; k0 < 1024; k0 += 64) {
#pragma unroll
    for (int it = 0; it < MFRAG; ++it) {
      const int u = (it * 4 + wid) * 64 + lane;
      const int row = u >> 3;
      const int cu = (u & 7) ^ (row & 7);   // inverse-swizzled source column
      gload_lds16(Ag + (size_t)(m0 + row) * 1024 + k0 + cu * 8, As + (size_t)u * 8);
    }
#pragma unroll
    for (int it = 0; it < 4; ++it) {
      const int u = (it * 4 + wid) * 64 + lane;
      const int row = u >> 3;
      const int cu = (u & 7) ^ (row & 7);
      gload_lds16(Bg + (size_t)(n0 + row) * 1024 + k0 + cu * 8, Bs + (size_t)u * 8);
    }
    __syncthreads();
#pragma unroll
    for (int kc = 0; kc < 2; ++kc) {
      bf16x8 a[MFRAG], b[4];
#pragma unroll
      for (int i = 0; i < MFRAG; ++i) {
        const int ra = wr * MFRAG * 16 + i * 16 + l15;   // ra&7 == l7
        a[i] = *(const bf16x8*)(As + ra * 64 + (((kc * 4 + l4) ^ l7) << 3));
      }
#pragma unroll
      for (int j = 0; j < 4; ++j) {
        const int rb = wc * 64 + j * 16 + l15;           // rb&7 == l7
        b[j] = *(const bf16x8*)(Bs + rb * 64 + (((kc * 4 + l4) ^ l7) << 3));
      }
#pragma unroll
      for (int i = 0; i < MFRAG; ++i)
#pragma unroll
        for (int j = 0; j < 4; ++j)
          acc[i][j] = MFMA_16x16x32(a[i], b[j], acc[i][j]);
    }
    __syncthreads();
  }

  if constexpr (WRITE_VT) {
    if (n0 >= 2048) {
      // SM = s-rows per wave sub-tile. Park offset vc*SM + (sb ^ swz):
      // swz = (vc & (SM/8-1))<<3 stays in [0,SM) and only touches bits>=3,
      // so 4-short blocks remain contiguous (s4 is 4-aligned).
      constexpr int SM = MFRAG * 16;
      constexpr int SWM = SM / 8 - 1;
      short* wreg = (wid < 2) ? &As[wid * 64 * SM] : &Bs[(wid - 2) * 64 * SM];
#pragma unroll
      for (int i = 0; i < MFRAG; ++i) {
#pragma unroll
        for (int j = 0; j < 4; ++j) {
          const int vc = j * 16 + l15;
          const int sb = i * 16 + l4 * 4;
          bf16x4v w;
#pragma unroll
          for (int r = 0; r < 4; ++r) w[r] = f2bf(acc[i][j][r]);
          *(bf16x4v*)(wreg + vc * SM + (sb ^ ((vc & SWM) << 3))) = w;
        }
      }
      __syncthreads();
      // drain: 64-lane group q empties wave q's region, SM/4 lanes per vc row
      // -> SM*2B contiguous along s per row (64-128B stores).
      constexpr int LPR = SM / 4;        // lanes per vc row
      constexpr int RPI = 64 / LPR;      // vc rows per iteration
      const int q = tid >> 6;
      const short* rreg = (q < 2) ? &As[q * 64 * SM] : &Bs[(q - 2) * 64 * SM];
      const int wrq = q >> 1, wcq = q & 1;
      const int srow = m0 + wrq * SM;
      const int bq = srow >> 11, sloc = srow & 2047;
      short* vg = (short*)vt;
#pragma unroll
      for (int it = 0; it < 64 / RPI; ++it) {
        const int vc = it * RPI + lane / LPR;
        const int s4 = (lane % LPR) * 4;
        const int vcg = n0 - 2048 + wcq * 64 + vc;
        bf16x4v w = *(const bf16x4v*)(rreg + vc * SM + (s4 ^ ((vc & SWM) << 3)));
        *(bf16x4v*)(vg + ((size_t)(bq * 1024 + vcg)) * 2048 + sloc + s4) = w;
      }
      return;
    }
  }

#pragma unroll
  for (int i = 0; i < MFRAG; ++i)
#pragma unroll
    for (int j = 0; j < 4; ++j) {
      const int row0 = m0 + wr * MFRAG * 16 + i * 16 + l4 * 4;
      const int col = n0 + wc * 64 + j * 16 + l15;
#pragma unroll
      for (int r = 0; r < 4; ++r) {
        if (OUT_F32)
          ((float*)C)[(size_t)(row0 + r) * N + col] = acc[i][j][r];
        else
          ((short*)C)[(size_t)(row0 + r) * N + col] = f2bf(acc[i][j][r]);
      }
    }
}

// ---------- flash attention, KV-split x2, swapped 32x32x16, no-max softmax ----------
// (round-17 version, unchanged: counted-vmcnt pipeline + __expf + ones-MFMA)
__global__ __launch_bounds__(256, 4) void attn_kernel(const __hip_bfloat16* __restrict__ QKVp,
                                                      const __hip_bfloat16* __restrict__ Vtp,
                                                      __hip_bfloat16* __restrict__ partb,
                                                      float* __restrict__ stats) {
  __shared__ __align__(16) short Kb[3][64 * 64];
  __shared__ __align__(16) short Vb[2][64 * 64];
  // XCD-chunked bijective swizzle: 1024 blocks, 8 XCDs -> chunks of 128
  int bid = (int)blockIdx.x;
  bid = (bid & 7) * 128 + (bid >> 3);
  const int sg = bid & 1;
  const int qtt = (bid >> 1) & 15;
  const int bh = bid >> 5;  // b*16 + h
  const int h = bh & 15, b = bh >> 4;
  const int tid = threadIdx.x;
  const int lane = tid & 63, wid = tid >> 6;
  const int l31 = lane & 31, l5 = lane >> 5;
  const size_t tokW = (size_t)b * 2048 + qtt * 128 + wid * 32;
  const short* QKV = (const short*)QKVp;
  const short* Kg = QKV + (size_t)b * 2048 * 3072 + 1024 + h * 64;
  const short* Vg = (const short*)Vtp + (size_t)bh * 64 * 2048;
  const int kbase = sg * 16;

  // Q fragments (B-operand of S^T mfma), pre-scaled by 0.125 (e-domain)
  bf16x8 qf[4];
#pragma unroll
  for (int kc = 0; kc < 4; ++kc) {
    bf16x8 raw = *(const bf16x8*)(QKV + (tokW + l31) * 3072 + h * 64 + kc * 16 + l5 * 8);
#pragma unroll
    for (int e = 0; e < 8; ++e) qf[kc][e] = f2bf(bf2f(raw[e]) * 0.125f);
  }

  // all-ones A-fragment for the lsum MFMA (bf16 1.0 = 0x3F80)
  bf16x8 onesf;
#pragma unroll
  for (int e = 0; e < 8; ++e) onesf[e] = (short)0x3F80;

  auto stageK = [&](int slot, int kt) {
    const int ktg = kbase + kt;
#pragma unroll
    for (int it = 0; it < 2; ++it) {
      const int flat = it * 256 + tid;
      const int r = flat >> 3;
      const int c = (flat & 7) ^ (r & 7);
      gload_lds16(Kg + (size_t)(ktg * 64 + r) * 3072 + c * 8, &Kb[slot][(size_t)flat * 8]);
    }
  };
  auto stageV = [&](int slot, int kt) {
    const int ktg = kbase + kt;
#pragma unroll
    for (int it = 0; it < 2; ++it) {
      const int flat = it * 256 + tid;
      const int r = flat >> 3;
      const int c = (flat & 7) ^ (r & 7);
      gload_lds16(Vg + (size_t)r * 2048 + ktg * 64 + c * 8, &Vb[slot][(size_t)flat * 8]);
    }
  };

  // prologue: FIFO = [K0,K0, V0,V0, K1,K1]; vmcnt(4) -> K0 landed.
  stageK(0, 0);
  stageV(0, 0);
  stageK(1, 1);
  asm volatile("s_waitcnt vmcnt(4)" ::: "memory");
  __builtin_amdgcn_s_barrier();
  __builtin_amdgcn_sched_barrier(0);

  f32x16 o0 = {}, o1 = {}, ol = {};

  for (int kt = 0; kt < 16; ++kt) {
    const int ks3 = kt % 3;       // K read slot
    const int vs = kt & 1;        // V read slot
    if (kt < 14) stageK((kt + 2) % 3, kt + 2);
    if (kt < 15) stageV((kt + 1) & 1, kt + 1);

    // ---- S^T[k][q] (e-domain scores), K from Kb[ks3] ----
    f32x16 s0 = {}, s1 = {};
    __builtin_amdgcn_s_setprio(1);
#pragma unroll
    for (int kc = 0; kc < 4; ++kc) {
      const int u0 = (kc * 2 + l5) ^ (l31 & 7);
      const bf16x8 kf0 = *(const bf16x8*)(&Kb[ks3][l31 * 64 + u0 * 8]);
      s0 = MFMA_32x32x16(kf0, qf[kc], s0);
      const int row1 = 32 + l31;
      const int u1 = (kc * 2 + l5) ^ (row1 & 7);
      const bf16x8 kf1 = *(const bf16x8*)(&Kb[ks3][row1 * 64 + u1 * 8]);
      s1 = MFMA_32x32x16(kf1, qf[kc], s1);
    }
    __builtin_amdgcn_s_setprio(0);

    // ---- P = exp(S) via __expf (native v_exp_f32), packed to bf16 pairs ----
    unsigned pkd0[4][2], pkd1[4][2];  // [group g][dword]: rows 8g+4*l5 + {0,1},{2,3}
#pragma unroll
    for (int g = 0; g < 4; ++g) {
      pkd0[g][0] = cvt_pk_bf16(__expf(s0[4 * g + 0]), __expf(s0[4 * g + 1]));
      pkd0[g][1] = cvt_pk_bf16(__expf(s0[4 * g + 2]), __expf(s0[4 * g + 3]));
      pkd1[g][0] = cvt_pk_bf16(__expf(s1[4 * g + 0]), __expf(s1[4 * g + 1]));
      pkd1[g][1] = cvt_pk_bf16(__expf(s1[4 * g + 2]), __expf(s1[4 * g + 3]));
    }

    // ---- late V wait: drain exactly through V(kt) ----
    if (kt < 14)      { asm volatile("s_waitcnt vmcnt(4)" ::: "memory"); }
    else if (kt < 15) { asm volatile("s_waitcnt vmcnt(2)" ::: "memory"); }
    else              { asm volatile("s_waitcnt vmcnt(0)" ::: "memory"); }
    __builtin_amdgcn_sched_barrier(0);

    // ---- O^T += V^T . P^T ;  ol += ones . P^T (lsum on the MFMA pipe) ----
    __builtin_amdgcn_s_setprio(1);
#pragma unroll
    for (int ks = 0; ks < 4; ++ks) {
      const int gA = (2 * ks) & 3, gB = (2 * ks + 1) & 3;
      unsigned a0, a1, b0, b1;
      if (ks < 2) { a0 = pkd0[gA][0]; a1 = pkd0[gA][1]; b0 = pkd0[gB][0]; b1 = pkd0[gB][1]; }
      else        { a0 = pkd1[gA][0]; a1 = pkd1[gA][1]; b0 = pkd1[gB][0]; b1 = pkd1[gB][1]; }
      union { unsigned d[4]; bf16x8 v; } pf;
#if __has_builtin(__builtin_amdgcn_permlane32_swap)
      {
        auto r0 = __builtin_amdgcn_permlane32_swap(a0, b0, false, false);
        auto r1 = __builtin_amdgcn_permlane32_swap(a1, b1, false, false);
        pf.d[0] = r0[0]; pf.d[1] = r1[0]; pf.d[2] = r0[1]; pf.d[3] = r1[1];
      }
#else
      {
        const unsigned long long A = (unsigned long long)a0 | ((unsigned long long)a1 << 32);
        const unsigned long long B = (unsigned long long)b0 | ((unsigned long long)b1 << 32);
        const unsigned long long own = l5 ? B : A;
        const unsigned long long send = l5 ? A : B;
        const unsigned long long recv = __shfl_xor(send, 32);
        const unsigned long long w0 = l5 ? recv : own;
        const unsigned long long w1 = l5 ? own : recv;
        pf.d[0] = (unsigned)w0; pf.d[1] = (unsigned)(w0 >> 32);
        pf.d[2] = (unsigned)w1; pf.d[3] = (unsigned)(w1 >> 32);
      }
#endif
      ol = MFMA_32x32x16(onesf, pf.v, ol);
      {
        const int u = (ks * 2 + l5) ^ (l31 & 7);
        const bf16x8 vf = *(const bf16x8*)(&Vb[vs][l31 * 64 + u * 8]);
        o0 = MFMA_32x32x16(vf, pf.v, o0);
      }
      {
        const int row = 32 + l31;
        const int u = (ks * 2 + l5) ^ (row & 7);
        const bf16x8 vf = *(const bf16x8*)(&Vb[vs][row * 64 + u * 8]);
        o1 = MFMA_32x32x16(vf, pf.v, o1);
      }
    }
    __builtin_amdgcn_s_setprio(0);

    if (kt < 15) {
      __builtin_amdgcn_s_barrier();
      __builtin_amdgcn_sched_barrier(0);
    }
  }

  // ---- epilogue: store unnormalized partial O (bf16) + row-sum ----
  const float lsum = ol[0];  // ol[r] = lsum[q=l31] for all r; covers both halves
  const size_t pbase = ((size_t)(bh * 16 + qtt) * 2 + sg) * 8192;
  const int ql = wid * 32 + l31;
  short* pg = (short*)partb;
#pragma unroll
  for (int mt = 0; mt < 2; ++mt) {
    const f32x16& o = mt ? o1 : o0;
#pragma unroll
    for (int rg = 0; rg < 4; ++rg) {
      const int d0 = 32 * mt + 8 * rg + 4 * l5;
      bf16x4v w;
#pragma unroll
      for (int el = 0; el < 4; ++el) w[el] = f2bf(o[4 * rg + el]);
      *(bf16x4v*)(pg + pbase + (size_t)ql * 64 + d0) = w;
    }
  }
  if (l5 == 0) {
    const size_t sb = ((size_t)(bh * 16 + qtt) * 2 + sg) * 128;
    stats[sb + ql] = lsum;
  }
}

// ---------- merge the two KV-splits -> final O (bf16) ----------
__global__ __launch_bounds__(256) void merge_kernel(const __hip_bfloat16* __restrict__ partb,
                                                    const float* __restrict__ stats,
                                                    __hip_bfloat16* __restrict__ O) {
  const int bid = blockIdx.x;
  const int qtt = bid & 15, bh = bid >> 4;
  const int h = bh & 15, b = bh >> 4;
  const int tid = threadIdx.x;
  const int r = tid >> 1, dh = (tid & 1) * 32;
  const size_t base = (size_t)(bh * 16 + qtt) * 2;
  const size_t p0 = base * 8192, p1 = p0 + 8192;
  const float l0 = stats[base * 128 + r], l1 = stats[base * 128 + 128 + r];
  const float inv = 1.0f / (l0 + l1);
  const short* pg = (const short*)partb;
  short* Og = (short*)O;
  const size_t orow = ((size_t)b * 2048 + qtt * 128 + r) * 1024 + h * 64 + dh;
#pragma unroll
  for (int j = 0; j < 8; ++j) {
    bf16x4v a = *(const bf16x4v*)(pg + p0 + (size_t)r * 64 + dh + 4 * j);
    bf16x4v c = *(const bf16x4v*)(pg + p1 + (size_t)r * 64 + dh + 4 * j);
    bf16x4v o;
#pragma unroll
    for (int el = 0; el < 4; ++el) o[el] = f2bf((bf2f(a[el]) + bf2f(c[el])) * inv);
    *(bf16x4v*)(Og + orow + 4 * j) = o;
  }
}

extern "C" void kernel_launch(void* const* d_in, const int* in_sizes, int n_in,
                              void* d_out, int out_size, void* d_ws, size_t ws_size,
                              hipStream_t stream) {
  const float* x = (const float*)d_in[0];
  const float* Wq = (const float*)d_in[1];
  const float* Wk = (const float*)d_in[2];
  const float* Wv = (const float*)d_in[3];
  const float* Wo = (const float*)d_in[4];
  float* out = (float*)d_out;

  __hip_bfloat16* ws = (__hip_bfloat16*)d_ws;
  const size_t MT = (size_t)4096 * 1024;
  const size_t WT = (size_t)1024 * 1024;
  __hip_bfloat16* xb = ws;             // x bf16 (dead after QKV gemm)
  __hip_bfloat16* wall = ws + MT;      // [Wo][Wq][Wk][Wv] bf16
  __hip_bfloat16* wob = wall;
  __hip_bfloat16* wqkv = wall + WT;    // Wq|Wk|Wv contiguous (3072 rows)
  __hip_bfloat16* qkvb = wall + 4 * WT;              // [4096, 3072] (V third unused)
  __hip_bfloat16* vtb = qkvb + (size_t)4096 * 3072;  // [2,16,64,2048]; later final O
  __hip_bfloat16* partb = vtb + MT;                  // partial O, 8M bf16 (16MB)
  float* stats = (float*)wqkv;         // 512KB, overlays dead Wq-bf16 during attn

  cast_all<<<8192, 256, 0, stream>>>(x, Wq, Wk, Wv, Wo, xb, wall);

  // fused QKV projection, 64x128 tiles (1536 blocks = 6/CU): Q|K into qkvb,
  // V written directly transposed (coalesced via LDS bounce) into vtb.
  gemm_bt<2, 0, 1><<<1536, 256, 0, stream>>>(xb, wqkv, qkvb, 3072, 24, vtb);

  attn_kernel<<<1024, 256, 0, stream>>>(qkvb, vtb, partb, stats);

  merge_kernel<<<512, 256, 0, stream>>>(partb, stats, vtb);  // final O -> vtb region

  // output projection, 32x128 tiles (1024 blocks = 4/CU)
  gemm_bt<1, 1, 0><<<1024, 256, 0, stream>>>(vtb, wob, out, 1024, 8, nullptr);
}

// Round 23
// 119.037 us; speedup vs baseline: 1.2506x; 1.0004x over previous
//
#include <hip/hip_runtime.h>
#include <hip/hip_bf16.h>

// MultiHeadAttention: x[2,2048,1024] fp32, Wq/Wk/Wv/Wo[1024,1024] fp32
// out = softmax((xWq^T)(xWk^T)^T * 0.125) (xWv^T) Wo^T   per head (H=16, Dh=64)

typedef __attribute__((ext_vector_type(8))) short bf16x8;
typedef __attribute__((ext_vector_type(4))) short bf16x4v;
typedef __attribute__((ext_vector_type(4))) float f32x4;
typedef __attribute__((ext_vector_type(16))) float f32x16;

#define MFMA_16x16x32(a, b, c) __builtin_amdgcn_mfma_f32_16x16x32_bf16((a), (b), (c), 0, 0, 0)
#define MFMA_32x32x16(a, b, c) __builtin_amdgcn_mfma_f32_32x32x16_bf16((a), (b), (c), 0, 0, 0)

static __device__ __forceinline__ void gload_lds16(const void* g, void* l) {
  __builtin_amdgcn_global_load_lds((const __attribute__((address_space(1))) void*)g,
                                   (__attribute__((address_space(3))) void*)l, 16, 0, 0);
}

static __device__ __forceinline__ short f2bf(float f) {
  __hip_bfloat16 h = __float2bfloat16(f);
  return *reinterpret_cast<short*>(&h);
}
static __device__ __forceinline__ float bf2f(short s) {
  unsigned u = ((unsigned)(unsigned short)s) << 16;
  union { unsigned u; float f; } cv; cv.u = u; return cv.f;
}
// packed f32x2 -> bf16x2 (single instruction; no builtin on gfx950)
static __device__ __forceinline__ unsigned cvt_pk_bf16(float lo, float hi) {
  unsigned r;
  asm("v_cvt_pk_bf16_f32 %0, %1, %2" : "=v"(r) : "v"(lo), "v"(hi));
  return r;
}

// ---------- fused cast: x (4M f32) + Wo|Wq|Wk|Wv (4M f32) -> bf16 ----------
__global__ __launch_bounds__(256) void cast_all(const float* __restrict__ x,
                                                const float* __restrict__ wq,
                                                const float* __restrict__ wk,
                                                const float* __restrict__ wv,
                                                const float* __restrict__ wo,
                                                __hip_bfloat16* __restrict__ xb,
                                                __hip_bfloat16* __restrict__ wall) {
  int i = blockIdx.x * 256 + threadIdx.x;  // 0 .. 8*2^18-1 (float4 units)
  const int reg = i >> 18;
  const float* src;
  __hip_bfloat16* dst;
  int di, si;
  if (reg < 4) {
    src = x; di = i; si = i; dst = xb;
  } else {
    src = (reg == 4) ? wo : (reg == 5) ? wq : (reg == 6) ? wk : wv;
    di = i - (4 << 18);
    si = i & 0x3FFFF;
    dst = wall;
  }
  const float4 v = reinterpret_cast<const float4*>(src)[si];
  bf16x4v o;
  o[0] = f2bf(v.x); o[1] = f2bf(v.y); o[2] = f2bf(v.z); o[3] = f2bf(v.w);
  reinterpret_cast<bf16x4v*>(dst)[di] = o;
}

// ---------- C[m,n] = sum_k A[m,k]*B[n,k];  M=4096, K=1024, N = col-stride ----------
// Block tile (MFRAG*32) x 128; 4 waves as 2x2; wave tile (MFRAG*16) x 64.
// LDS tiles are T2 XOR-swizzled: stage uses linear LDS dest + inverse-swizzled
// GLOBAL source (16B unit cu ^= row&7); fragment reads use unit ^ (l15&7).
// -> ds_read_b128 is bank-conflict-free (8 distinct units x 4 banks, 2-way).
// WRITE_VT: V-column blocks (n0>=2048) of the fused QKV GEMM write V^T
// [b,h,d,s] via a generalized LDS bounce (coalesced s-major stores).
template <int MFRAG, int OUT_F32, int WRITE_VT>
__global__ __launch_bounds__(256) void gemm_bt(const __hip_bfloat16* __restrict__ A,
                                               const __hip_bfloat16* __restrict__ B,
                                               void* __restrict__ C, int N, int nbx,
                                               __hip_bfloat16* __restrict__ vt) {
  __shared__ __align__(16) short As[MFRAG * 32 * 64];
  __shared__ __align__(16) short Bs[128 * 64];
  const int tid = threadIdx.x;
  const int lane = tid & 63, wid = tid >> 6;
  const int l15 = lane & 15, l4 = lane >> 4;
  const int l7 = l15 & 7;
  const int wr = wid >> 1, wc = wid & 1;
  const int m0 = (blockIdx.x / nbx) * (MFRAG * 32);
  const int n0 = (blockIdx.x % nbx) * 128;
  const short* Ag = (const short*)A;
  const short* Bg = (const short*)B;

  f32x4 acc[MFRAG][4] = {};

  for (int k0 = 0; k0 < 1024; k0 += 64) {
#pragma unroll
    for (int it = 0; it < MFRAG; ++it) {
      const int u = (it * 4 + wid) * 64 + lane;
      const int row = u >> 3;
      const int cu = (u & 7) ^ (row & 7);   // inverse-swizzled source column
      gload_lds16(Ag + (size_t)(m0 + row) * 1024 + k0 + cu * 8, As + (size_t)u * 8);
    }
#pragma unroll
    for (int it = 0; it < 4; ++it) {
      const int u = (it * 4 + wid) * 64 + lane;
      const int row = u >> 3;
      const int cu = (u & 7) ^ (row & 7);
      gload_lds16(Bg + (size_t)(n0 + row) * 1024 + k0 + cu * 8, Bs + (size_t)u * 8);
    }
    __syncthreads();
#pragma unroll
    for (int kc = 0; kc < 2; ++kc) {
      bf16x8 a[MFRAG], b[4];
#pragma unroll
      for (int i = 0; i < MFRAG; ++i) {
        const int ra = wr * MFRAG * 16 + i * 16 + l15;   // ra&7 == l7
        a[i] = *(const bf16x8*)(As + ra * 64 + (((kc * 4 + l4) ^ l7) << 3));
      }
#pragma unroll
      for (int j = 0; j < 4; ++j) {
        const int rb = wc * 64 + j * 16 + l15;           // rb&7 == l7
        b[j] = *(const bf16x8*)(Bs + rb * 64 + (((kc * 4 + l4) ^ l7) << 3));
      }
#pragma unroll
      for (int i = 0; i < MFRAG; ++i)
#pragma unroll
        for (int j = 0; j < 4; ++j)
          acc[i][j] = MFMA_16x16x32(a[i], b[j], acc[i][j]);
    }
    __syncthreads();
  }

  if constexpr (WRITE_VT) {
    if (n0 >= 2048) {
      // SM = s-rows per wave sub-tile. Park offset vc*SM + (sb ^ swz):
      // swz = (vc & (SM/8-1))<<3 stays in [0,SM) and only touches bits>=3,
      // so 4-short blocks remain contiguous (s4 is 4-aligned).
      constexpr int SM = MFRAG * 16;
      constexpr int SWM = SM / 8 - 1;
      short* wreg = (wid < 2) ? &As[wid * 64 * SM] : &Bs[(wid - 2) * 64 * SM];
#pragma unroll
      for (int i = 0; i < MFRAG; ++i) {
#pragma unroll
        for (int j = 0; j < 4; ++j) {
          const int vc = j * 16 + l15;
          const int sb = i * 16 + l4 * 4;
          bf16x4v w;
#pragma unroll
          for (int r = 0; r < 4; ++r) w[r] = f2bf(acc[i][j][r]);
          *(bf16x4v*)(wreg + vc * SM + (sb ^ ((vc & SWM) << 3))) = w;
        }
      }
      __syncthreads();
      // drain: 64-lane group q empties wave q's region, SM/4 lanes per vc row
      // -> SM*2B contiguous along s per row (64-128B stores).
      constexpr int LPR = SM / 4;        // lanes per vc row
      constexpr int RPI = 64 / LPR;      // vc rows per iteration
      const int q = tid >> 6;
      const short* rreg = (q < 2) ? &As[q * 64 * SM] : &Bs[(q - 2) * 64 * SM];
      const int wrq = q >> 1, wcq = q & 1;
      const int srow = m0 + wrq * SM;
      const int bq = srow >> 11, sloc = srow & 2047;
      short* vg = (short*)vt;
#pragma unroll
      for (int it = 0; it < 64 / RPI; ++it) {
        const int vc = it * RPI + lane / LPR;
        const int s4 = (lane % LPR) * 4;
        const int vcg = n0 - 2048 + wcq * 64 + vc;
        bf16x4v w = *(const bf16x4v*)(rreg + vc * SM + (s4 ^ ((vc & SWM) << 3)));
        *(bf16x4v*)(vg + ((size_t)(bq * 1024 + vcg)) * 2048 + sloc + s4) = w;
      }
      return;
    }
  }

#pragma unroll
  for (int i = 0; i < MFRAG; ++i)
#pragma unroll
    for (int j = 0; j < 4; ++j) {
      const int row0 = m0 + wr * MFRAG * 16 + i * 16 + l4 * 4;
      const int col = n0 + wc * 64 + j * 16 + l15;
#pragma unroll
      for (int r = 0; r < 4; ++r) {
        if (OUT_F32)
          ((float*)C)[(size_t)(row0 + r) * N + col] = acc[i][j][r];
        else
          ((short*)C)[(size_t)(row0 + r) * N + col] = f2bf(acc[i][j][r]);
      }
    }
}

// ---------- flash attention, KV-split x2, swapped 32x32x16, no-max softmax ----------
// Round-20 exact (proven 5 consecutive rounds): K triple-buffered distance-2,
// V double-buffered distance-1 with late counted vmcnt wait; __expf softmax;
// lsum via ones-row MFMA; permlane32_swap P redistribution.
__global__ __launch_bounds__(256, 4) void attn_kernel(const __hip_bfloat16* __restrict__ QKVp,
                                                      const __hip_bfloat16* __restrict__ Vtp,
                                                      __hip_bfloat16* __restrict__ partb,
                                                      float* __restrict__ stats) {
  __shared__ __align__(16) short Kb[3][64 * 64];
  __shared__ __align__(16) short Vb[2][64 * 64];
  // XCD-chunked bijective swizzle: 1024 blocks, 8 XCDs -> chunks of 128
  int bid = (int)blockIdx.x;
  bid = (bid & 7) * 128 + (bid >> 3);
  const int sg = bid & 1;
  const int qtt = (bid >> 1) & 15;
  const int bh = bid >> 5;  // b*16 + h
  const int h = bh & 15, b = bh >> 4;
  const int tid = threadIdx.x;
  const int lane = tid & 63, wid = tid >> 6;
  const int l31 = lane & 31, l5 = lane >> 5;
  const size_t tokW = (size_t)b * 2048 + qtt * 128 + wid * 32;
  const short* QKV = (const short*)QKVp;
  const short* Kg = QKV + (size_t)b * 2048 * 3072 + 1024 + h * 64;
  const short* Vg = (const short*)Vtp + (size_t)bh * 64 * 2048;
  const int kbase = sg * 16;

  // Q fragments (B-operand of S^T mfma), pre-scaled by 0.125 (e-domain)
  bf16x8 qf[4];
#pragma unroll
  for (int kc = 0; kc < 4; ++kc) {
    bf16x8 raw = *(const bf16x8*)(QKV + (tokW + l31) * 3072 + h * 64 + kc * 16 + l5 * 8);
#pragma unroll
    for (int e = 0; e < 8; ++e) qf[kc][e] = f2bf(bf2f(raw[e]) * 0.125f);
  }

  // all-ones A-fragment for the lsum MFMA (bf16 1.0 = 0x3F80)
  bf16x8 onesf;
#pragma unroll
  for (int e = 0; e < 8; ++e) onesf[e] = (short)0x3F80;

  auto stageK = [&](int slot, int kt) {
    const int ktg = kbase + kt;
#pragma unroll
    for (int it = 0; it < 2; ++it) {
      const int flat = it * 256 + tid;
      const int r = flat >> 3;
      const int c = (flat & 7) ^ (r & 7);
      gload_lds16(Kg + (size_t)(ktg * 64 + r) * 3072 + c * 8, &Kb[slot][(size_t)flat * 8]);
    }
  };
  auto stageV = [&](int slot, int kt) {
    const int ktg = kbase + kt;
#pragma unroll
    for (int it = 0; it < 2; ++it) {
      const int flat = it * 256 + tid;
      const int r = flat >> 3;
      const int c = (flat & 7) ^ (r & 7);
      gload_lds16(Vg + (size_t)r * 2048 + ktg * 64 + c * 8, &Vb[slot][(size_t)flat * 8]);
    }
  };

  // prologue: FIFO = [K0,K0, V0,V0, K1,K1]; vmcnt(4) -> K0 landed.
  stageK(0, 0);
  stageV(0, 0);
  stageK(1, 1);
  asm volatile("s_waitcnt vmcnt(4)" ::: "memory");
  __builtin_amdgcn_s_barrier();
  __builtin_amdgcn_sched_barrier(0);

  f32x16 o0 = {}, o1 = {}, ol = {};

  for (int kt = 0; kt < 16; ++kt) {
    const int ks3 = kt % 3;       // K read slot
    const int vs = kt & 1;        // V read slot
    if (kt < 14) stageK((kt + 2) % 3, kt + 2);
    if (kt < 15) stageV((kt + 1) & 1, kt + 1);

    // ---- S^T[k][q] (e-domain scores), K from Kb[ks3] ----
    f32x16 s0 = {}, s1 = {};
    __builtin_amdgcn_s_setprio(1);
#pragma unroll
    for (int kc = 0; kc < 4; ++kc) {
      const int u0 = (kc * 2 + l5) ^ (l31 & 7);
      const bf16x8 kf0 = *(const bf16x8*)(&Kb[ks3][l31 * 64 + u0 * 8]);
      s0 = MFMA_32x32x16(kf0, qf[kc], s0);
      const int row1 = 32 + l31;
      const int u1 = (kc * 2 + l5) ^ (row1 & 7);
      const bf16x8 kf1 = *(const bf16x8*)(&Kb[ks3][row1 * 64 + u1 * 8]);
      s1 = MFMA_32x32x16(kf1, qf[kc], s1);
    }
    __builtin_amdgcn_s_setprio(0);

    // ---- P = exp(S) via __expf (native v_exp_f32), packed to bf16 pairs ----
    unsigned pkd0[4][2], pkd1[4][2];  // [group g][dword]: rows 8g+4*l5 + {0,1},{2,3}
#pragma unroll
    for (int g = 0; g < 4; ++g) {
      pkd0[g][0] = cvt_pk_bf16(__expf(s0[4 * g + 0]), __expf(s0[4 * g + 1]));
      pkd0[g][1] = cvt_pk_bf16(__expf(s0[4 * g + 2]), __expf(s0[4 * g + 3]));
      pkd1[g][0] = cvt_pk_bf16(__expf(s1[4 * g + 0]), __expf(s1[4 * g + 1]));
      pkd1[g][1] = cvt_pk_bf16(__expf(s1[4 * g + 2]), __expf(s1[4 * g + 3]));
    }

    // ---- late V wait: drain exactly through V(kt) ----
    if (kt < 14)      { asm volatile("s_waitcnt vmcnt(4)" ::: "memory"); }
    else if (kt < 15) { asm volatile("s_waitcnt vmcnt(2)" ::: "memory"); }
    else              { asm volatile("s_waitcnt vmcnt(0)" ::: "memory"); }
    __builtin_amdgcn_sched_barrier(0);

    // ---- O^T += V^T . P^T ;  ol += ones . P^T (lsum on the MFMA pipe) ----
    __builtin_amdgcn_s_setprio(1);
#pragma unroll
    for (int ks = 0; ks < 4; ++ks) {
      const int gA = (2 * ks) & 3, gB = (2 * ks + 1) & 3;
      unsigned a0, a1, b0, b1;
      if (ks < 2) { a0 = pkd0[gA][0]; a1 = pkd0[gA][1]; b0 = pkd0[gB][0]; b1 = pkd0[gB][1]; }
      else        { a0 = pkd1[gA][0]; a1 = pkd1[gA][1]; b0 = pkd1[gB][0]; b1 = pkd1[gB][1]; }
      union { unsigned d[4]; bf16x8 v; } pf;
#if __has_builtin(__builtin_amdgcn_permlane32_swap)
      {
        auto r0 = __builtin_amdgcn_permlane32_swap(a0, b0, false, false);
        auto r1 = __builtin_amdgcn_permlane32_swap(a1, b1, false, false);
        pf.d[0] = r0[0]; pf.d[1] = r1[0]; pf.d[2] = r0[1]; pf.d[3] = r1[1];
      }
#else
      {
        const unsigned long long A = (unsigned long long)a0 | ((unsigned long long)a1 << 32);
        const unsigned long long B = (unsigned long long)b0 | ((unsigned long long)b1 << 32);
        const unsigned long long own = l5 ? B : A;
        const unsigned long long send = l5 ? A : B;
        const unsigned long long recv = __shfl_xor(send, 32);
        const unsigned long long w0 = l5 ? recv : own;
        const unsigned long long w1 = l5 ? own : recv;
        pf.d[0] = (unsigned)w0; pf.d[1] = (unsigned)(w0 >> 32);
        pf.d[2] = (unsigned)w1; pf.d[3] = (unsigned)(w1 >> 32);
      }
#endif
      ol = MFMA_32x32x16(onesf, pf.v, ol);
      {
        const int u = (ks * 2 + l5) ^ (l31 & 7);
        const bf16x8 vf = *(const bf16x8*)(&Vb[vs][l31 * 64 + u * 8]);
        o0 = MFMA_32x32x16(vf, pf.v, o0);
      }
      {
        const int row = 32 + l31;
        const int u = (ks * 2 + l5) ^ (row & 7);
        const bf16x8 vf = *(const bf16x8*)(&Vb[vs][row * 64 + u * 8]);
        o1 = MFMA_32x32x16(vf, pf.v, o1);
      }
    }
    __builtin_amdgcn_s_setprio(0);

    if (kt < 15) {
      __builtin_amdgcn_s_barrier();
      __builtin_amdgcn_sched_barrier(0);
    }
  }

  // ---- epilogue: store unnormalized partial O (bf16) + row-sum ----
  const float lsum = ol[0];  // ol[r] = lsum[q=l31] for all r; covers both halves
  const size_t pbase = ((size_t)(bh * 16 + qtt) * 2 + sg) * 8192;
  const int ql = wid * 32 + l31;
  short* pg = (short*)partb;
#pragma unroll
  for (int mt = 0; mt < 2; ++mt) {
    const f32x16& o = mt ? o1 : o0;
#pragma unroll
    for (int rg = 0; rg < 4; ++rg) {
      const int d0 = 32 * mt + 8 * rg + 4 * l5;
      bf16x4v w;
#pragma unroll
      for (int el = 0; el < 4; ++el) w[el] = f2bf(o[4 * rg + el]);
      *(bf16x4v*)(pg + pbase + (size_t)ql * 64 + d0) = w;
    }
  }
  if (l5 == 0) {
    const size_t sb = ((size_t)(bh * 16 + qtt) * 2 + sg) * 128;
    stats[sb + ql] = lsum;
  }
}

// ---------- merge the two KV-splits -> final O (bf16) ----------
__global__ __launch_bounds__(256) void merge_kernel(const __hip_bfloat16* __restrict__ partb,
                                                    const float* __restrict__ stats,
                                                    __hip_bfloat16* __restrict__ O) {
  const int bid = blockIdx.x;
  const int qtt = bid & 15, bh = bid >> 4;
  const int h = bh & 15, b = bh >> 4;
  const int tid = threadIdx.x;
  const int r = tid >> 1, dh = (tid & 1) * 32;
  const size_t base = (size_t)(bh * 16 + qtt) * 2;
  const size_t p0 = base * 8192, p1 = p0 + 8192;
  const float l0 = stats[base * 128 + r], l1 = stats[base * 128 + 128 + r];
  const float inv = 1.0f / (l0 + l1);
  const short* pg = (const short*)partb;
  short* Og = (short*)O;
  const size_t orow = ((size_t)b * 2048 + qtt * 128 + r) * 1024 + h * 64 + dh;
#pragma unroll
  for (int j = 0; j < 8; ++j) {
    bf16x4v a = *(const bf16x4v*)(pg + p0 + (size_t)r * 64 + dh + 4 * j);
    bf16x4v c = *(const bf16x4v*)(pg + p1 + (size_t)r * 64 + dh + 4 * j);
    bf16x4v o;
#pragma unroll
    for (int el = 0; el < 4; ++el) o[el] = f2bf((bf2f(a[el]) + bf2f(c[el])) * inv);
    *(bf16x4v*)(Og + orow + 4 * j) = o;
  }
}

extern "C" void kernel_launch(void* const* d_in, const int* in_sizes, int n_in,
                              void* d_out, int out_size, void* d_ws, size_t ws_size,
                              hipStream_t stream) {
  const float* x = (const float*)d_in[0];
  const float* Wq = (const float*)d_in[1];
  const float* Wk = (const float*)d_in[2];
  const float* Wv = (const float*)d_in[3];
  const float* Wo = (const float*)d_in[4];
  float* out = (float*)d_out;

  __hip_bfloat16* ws = (__hip_bfloat16*)d_ws;
  const size_t MT = (size_t)4096 * 1024;
  const size_t WT = (size_t)1024 * 1024;
  __hip_bfloat16* xb = ws;             // x bf16 (dead after QKV gemm)
  __hip_bfloat16* wall = ws + MT;      // [Wo][Wq][Wk][Wv] bf16
  __hip_bfloat16* wob = wall;
  __hip_bfloat16* wqkv = wall + WT;    // Wq|Wk|Wv contiguous (3072 rows)
  __hip_bfloat16* qkvb = wall + 4 * WT;              // [4096, 3072] (V third unused)
  __hip_bfloat16* vtb = qkvb + (size_t)4096 * 3072;  // [2,16,64,2048]; later final O
  __hip_bfloat16* partb = vtb + MT;                  // partial O, 8M bf16 (16MB)
  float* stats = (float*)wqkv;         // 512KB, overlays dead Wq-bf16 during attn

  cast_all<<<8192, 256, 0, stream>>>(x, Wq, Wk, Wv, Wo, xb, wall);

  // fused QKV projection, 64x128 tiles (1536 blocks = 6/CU): Q|K into qkvb,
  // V written directly transposed (coalesced via LDS bounce) into vtb.
  gemm_bt<2, 0, 1><<<1536, 256, 0, stream>>>(xb, wqkv, qkvb, 3072, 24, vtb);

  attn_kernel<<<1024, 256, 0, stream>>>(qkvb, vtb, partb, stats);

  merge_kernel<<<512, 256, 0, stream>>>(partb, stats, vtb);  // final O -> vtb region

  // output projection, 32x128 tiles (1024 blocks = 4/CU)
  gemm_bt<1, 1, 0><<<1024, 256, 0, stream>>>(vtb, wob, out, 1024, 8, nullptr);
}

// Round 24
// 118.530 us; speedup vs baseline: 1.2559x; 1.0043x over previous
//
#include <hip/hip_runtime.h>
#include <hip/hip_bf16.h>

// MultiHeadAttention: x[2,2048,1024] fp32, Wq/Wk/Wv/Wo[1024,1024] fp32
// out = softmax((xWq^T)(xWk^T)^T * 0.125) (xWv^T) Wo^T   per head (H=16, Dh=64)

typedef __attribute__((ext_vector_type(8))) short bf16x8;
typedef __attribute__((ext_vector_type(4))) short bf16x4v;
typedef __attribute__((ext_vector_type(4))) float f32x4;
typedef __attribute__((ext_vector_type(16))) float f32x16;

#define MFMA_16x16x32(a, b, c) __builtin_amdgcn_mfma_f32_16x16x32_bf16((a), (b), (c), 0, 0, 0)
#define MFMA_32x32x16(a, b, c) __builtin_amdgcn_mfma_f32_32x32x16_bf16((a), (b), (c), 0, 0, 0)

static __device__ __forceinline__ void gload_lds16(const void* g, void* l) {
  __builtin_amdgcn_global_load_lds((const __attribute__((address_space(1))) void*)g,
                                   (__attribute__((address_space(3))) void*)l, 16, 0, 0);
}

static __device__ __forceinline__ short f2bf(float f) {
  __hip_bfloat16 h = __float2bfloat16(f);
  return *reinterpret_cast<short*>(&h);
}
static __device__ __forceinline__ float bf2f(short s) {
  unsigned u = ((unsigned)(unsigned short)s) << 16;
  union { unsigned u; float f; } cv; cv.u = u; return cv.f;
}
// packed f32x2 -> bf16x2 (single instruction; no builtin on gfx950)
static __device__ __forceinline__ unsigned cvt_pk_bf16(float lo, float hi) {
  unsigned r;
  asm("v_cvt_pk_bf16_f32 %0, %1, %2" : "=v"(r) : "v"(lo), "v"(hi));
  return r;
}

// ---------- fused cast: x (4M f32) + Wo|Wq|Wk|Wv (4M f32) -> bf16 ----------
// grid-stride: 2048 blocks x 4 float4s/thread.
__global__ __launch_bounds__(256) void cast_all(const float* __restrict__ x,
                                                const float* __restrict__ wq,
                                                const float* __restrict__ wk,
                                                const float* __restrict__ wv,
                                                const float* __restrict__ wo,
                                                __hip_bfloat16* __restrict__ xb,
                                                __hip_bfloat16* __restrict__ wall) {
  const int base = blockIdx.x * 256 + threadIdx.x;
#pragma unroll
  for (int it = 0; it < 4; ++it) {
    const int i = base + it * (2048 * 256);  // 0 .. 8*2^18-1 (float4 units)
    const int reg = i >> 18;
    const float* src;
    __hip_bfloat16* dst;
    int di, si;
    if (reg < 4) {
      src = x; di = i; si = i; dst = xb;
    } else {
      src = (reg == 4) ? wo : (reg == 5) ? wq : (reg == 6) ? wk : wv;
      di = i - (4 << 18);
      si = i & 0x3FFFF;
      dst = wall;
    }
    const float4 v = reinterpret_cast<const float4*>(src)[si];
    bf16x4v o;
    o[0] = f2bf(v.x); o[1] = f2bf(v.y); o[2] = f2bf(v.z); o[3] = f2bf(v.w);
    reinterpret_cast<bf16x4v*>(dst)[di] = o;
  }
}

// ---------- C[m,n] = sum_k A[m,k]*B[n,k];  M=4096, K=1024, N = col-stride ----------
// Block tile (MFRAG*32) x 128; 4 waves as 2x2; wave tile (MFRAG*16) x 64.
// LDS tiles are T2 XOR-swizzled: stage uses linear LDS dest + inverse-swizzled
// GLOBAL source (16B unit cu ^= row&7); fragment reads use unit ^ (l15&7).
// -> ds_read_b128 is bank-conflict-free (8 distinct units x 4 banks, 2-way).
// WRITE_VT: V-column blocks (n0>=2048) of the fused QKV GEMM write V^T
// [b,h,d,s] via a generalized LDS bounce (coalesced s-major stores).
template <int MFRAG, int OUT_F32, int WRITE_VT>
__global__ __launch_bounds__(256) void gemm_bt(const __hip_bfloat16* __restrict__ A,
                                               const __hip_bfloat16* __restrict__ B,
                                               void* __restrict__ C, int N, int nbx,
                                               __hip_bfloat16* __restrict__ vt) {
  __shared__ __align__(16) short As[MFRAG * 32 * 64];
  __shared__ __align__(16) short Bs[128 * 64];
  const int tid = threadIdx.x;
  const int lane = tid & 63, wid = tid >> 6;
  const int l15 = lane & 15, l4 = lane >> 4;
  const int l7 = l15 & 7;
  const int wr = wid >> 1, wc = wid & 1;
  const int m0 = (blockIdx.x / nbx) * (MFRAG * 32);
  const int n0 = (blockIdx.x % nbx) * 128;
  const short* Ag = (const short*)A;
  const short* Bg = (const short*)B;

  f32x4 acc[MFRAG][4] = {};

  for (int k0 = 0; k0 < 1024; k0 += 64) {
#pragma unroll
    for (int it = 0; it < MFRAG; ++it) {
      const int u = (it * 4 + wid) * 64 + lane;
      const int row = u >> 3;
      const int cu = (u & 7) ^ (row & 7);   // inverse-swizzled source column
      gload_lds16(Ag + (size_t)(m0 + row) * 1024 + k0 + cu * 8, As + (size_t)u * 8);
    }
#pragma unroll
    for (int it = 0; it < 4; ++it) {
      const int u = (it * 4 + wid) * 64 + lane;
      const int row = u >> 3;
      const int cu = (u & 7) ^ (row & 7);
      gload_lds16(Bg + (size_t)(n0 + row) * 1024 + k0 + cu * 8, Bs + (size_t)u * 8);
    }
    __syncthreads();
#pragma unroll
    for (int kc = 0; kc < 2; ++kc) {
      bf16x8 a[MFRAG], b[4];
#pragma unroll
      for (int i = 0; i < MFRAG; ++i) {
        const int ra = wr * MFRAG * 16 + i * 16 + l15;   // ra&7 == l7
        a[i] = *(const bf16x8*)(As + ra * 64 + (((kc * 4 + l4) ^ l7) << 3));
      }
#pragma unroll
      for (int j = 0; j < 4; ++j) {
        const int rb = wc * 64 + j * 16 + l15;           // rb&7 == l7
        b[j] = *(const bf16x8*)(Bs + rb * 64 + (((kc * 4 + l4) ^ l7) << 3));
      }
#pragma unroll
      for (int i = 0; i < MFRAG; ++i)
#pragma unroll
        for (int j = 0; j < 4; ++j)
          acc[i][j] = MFMA_16x16x32(a[i], b[j], acc[i][j]);
    }
    __syncthreads();
  }

  if constexpr (WRITE_VT) {
    if (n0 >= 2048) {
      // SM = s-rows per wave sub-tile. Park offset vc*SM + (sb ^ swz):
      // swz = (vc & (SM/8-1))<<3 stays in [0,SM) and only touches bits>=3,
      // so 4-short blocks remain contiguous (s4 is 4-aligned).
      constexpr int SM = MFRAG * 16;
      constexpr int SWM = SM / 8 - 1;
      short* wreg = (wid < 2) ? &As[wid * 64 * SM] : &Bs[(wid - 2) * 64 * SM];
#pragma unroll
      for (int i = 0; i < MFRAG; ++i) {
#pragma unroll
        for (int j = 0; j < 4; ++j) {
          const int vc = j * 16 + l15;
          const int sb = i * 16 + l4 * 4;
          bf16x4v w;
#pragma unroll
          for (int r = 0; r < 4; ++r) w[r] = f2bf(acc[i][j][r]);
          *(bf16x4v*)(wreg + vc * SM + (sb ^ ((vc & SWM) << 3))) = w;
        }
      }
      __syncthreads();
      // drain: 64-lane group q empties wave q's region, SM/4 lanes per vc row
      // -> SM*2B contiguous along s per row (64-128B stores).
      constexpr int LPR = SM / 4;        // lanes per vc row
      constexpr int RPI = 64 / LPR;      // vc rows per iteration
      const int q = tid >> 6;
      const short* rreg = (q < 2) ? &As[q * 64 * SM] : &Bs[(q - 2) * 64 * SM];
      const int wrq = q >> 1, wcq = q & 1;
      const int srow = m0 + wrq * SM;
      const int bq = srow >> 11, sloc = srow & 2047;
      short* vg = (short*)vt;
#pragma unroll
      for (int it = 0; it < 64 / RPI; ++it) {
        const int vc = it * RPI + lane / LPR;
        const int s4 = (lane % LPR) * 4;
        const int vcg = n0 - 2048 + wcq * 64 + vc;
        bf16x4v w = *(const bf16x4v*)(rreg + vc * SM + (s4 ^ ((vc & SWM) << 3)));
        *(bf16x4v*)(vg + ((size_t)(bq * 1024 + vcg)) * 2048 + sloc + s4) = w;
      }
      return;
    }
  }

#pragma unroll
  for (int i = 0; i < MFRAG; ++i)
#pragma unroll
    for (int j = 0; j < 4; ++j) {
      const int row0 = m0 + wr * MFRAG * 16 + i * 16 + l4 * 4;
      const int col = n0 + wc * 64 + j * 16 + l15;
#pragma unroll
      for (int r = 0; r < 4; ++r) {
        if (OUT_F32)
          ((float*)C)[(size_t)(row0 + r) * N + col] = acc[i][j][r];
        else
          ((short*)C)[(size_t)(row0 + r) * N + col] = f2bf(acc[i][j][r]);
      }
    }
}

// ---------- flash attention, KV-split x2, swapped 32x32x16, no-max softmax ----------
// Round-20 exact (proven): K triple-buffered distance-2, V double-buffered
// distance-1 with late counted vmcnt wait; __expf softmax; lsum via ones-row
// MFMA; permlane32_swap P redistribution.
__global__ __launch_bounds__(256, 4) void attn_kernel(const __hip_bfloat16* __restrict__ QKVp,
                                                      const __hip_bfloat16* __restrict__ Vtp,
                                                      __hip_bfloat16* __restrict__ partb,
                                                      float* __restrict__ stats) {
  __shared__ __align__(16) short Kb[3][64 * 64];
  __shared__ __align__(16) short Vb[2][64 * 64];
  // XCD-chunked bijective swizzle: 1024 blocks, 8 XCDs -> chunks of 128
  int bid = (int)blockIdx.x;
  bid = (bid & 7) * 128 + (bid >> 3);
  const int sg = bid & 1;
  const int qtt = (bid >> 1) & 15;
  const int bh = bid >> 5;  // b*16 + h
  const int h = bh & 15, b = bh >> 4;
  const int tid = threadIdx.x;
  const int lane = tid & 63, wid = tid >> 6;
  const int l31 = lane & 31, l5 = lane >> 5;
  const size_t tokW = (size_t)b * 2048 + qtt * 128 + wid * 32;
  const short* QKV = (const short*)QKVp;
  const short* Kg = QKV + (size_t)b * 2048 * 3072 + 1024 + h * 64;
  const short* Vg = (const short*)Vtp + (size_t)bh * 64 * 2048;
  const int kbase = sg * 16;

  // Q fragments (B-operand of S^T mfma), pre-scaled by 0.125 (e-domain)
  bf16x8 qf[4];
#pragma unroll
  for (int kc = 0; kc < 4; ++kc) {
    bf16x8 raw = *(const bf16x8*)(QKV + (tokW + l31) * 3072 + h * 64 + kc * 16 + l5 * 8);
#pragma unroll
    for (int e = 0; e < 8; ++e) qf[kc][e] = f2bf(bf2f(raw[e]) * 0.125f);
  }

  // all-ones A-fragment for the lsum MFMA (bf16 1.0 = 0x3F80)
  bf16x8 onesf;
#pragma unroll
  for (int e = 0; e < 8; ++e) onesf[e] = (short)0x3F80;

  auto stageK = [&](int slot, int kt) {
    const int ktg = kbase + kt;
#pragma unroll
    for (int it = 0; it < 2; ++it) {
      const int flat = it * 256 + tid;
      const int r = flat >> 3;
      const int c = (flat & 7) ^ (r & 7);
      gload_lds16(Kg + (size_t)(ktg * 64 + r) * 3072 + c * 8, &Kb[slot][(size_t)flat * 8]);
    }
  };
  auto stageV = [&](int slot, int kt) {
    const int ktg = kbase + kt;
#pragma unroll
    for (int it = 0; it < 2; ++it) {
      const int flat = it * 256 + tid;
      const int r = flat >> 3;
      const int c = (flat & 7) ^ (r & 7);
      gload_lds16(Vg + (size_t)r * 2048 + ktg * 64 + c * 8, &Vb[slot][(size_t)flat * 8]);
    }
  };

  // prologue: FIFO = [K0,K0, V0,V0, K1,K1]; vmcnt(4) -> K0 landed.
  stageK(0, 0);
  stageV(0, 0);
  stageK(1, 1);
  asm volatile("s_waitcnt vmcnt(4)" ::: "memory");
  __builtin_amdgcn_s_barrier();
  __builtin_amdgcn_sched_barrier(0);

  f32x16 o0 = {}, o1 = {}, ol = {};

  for (int kt = 0; kt < 16; ++kt) {
    const int ks3 = kt % 3;       // K read slot
    const int vs = kt & 1;        // V read slot
    if (kt < 14) stageK((kt + 2) % 3, kt + 2);
    if (kt < 15) stageV((kt + 1) & 1, kt + 1);

    // ---- S^T[k][q] (e-domain scores), K from Kb[ks3] ----
    f32x16 s0 = {}, s1 = {};
    __builtin_amdgcn_s_setprio(1);
#pragma unroll
    for (int kc = 0; kc < 4; ++kc) {
      const int u0 = (kc * 2 + l5) ^ (l31 & 7);
      const bf16x8 kf0 = *(const bf16x8*)(&Kb[ks3][l31 * 64 + u0 * 8]);
      s0 = MFMA_32x32x16(kf0, qf[kc], s0);
      const int row1 = 32 + l31;
      const int u1 = (kc * 2 + l5) ^ (row1 & 7);
      const bf16x8 kf1 = *(const bf16x8*)(&Kb[ks3][row1 * 64 + u1 * 8]);
      s1 = MFMA_32x32x16(kf1, qf[kc], s1);
    }
    __builtin_amdgcn_s_setprio(0);

    // ---- P = exp(S) via __expf (native v_exp_f32), packed to bf16 pairs ----
    unsigned pkd0[4][2], pkd1[4][2];  // [group g][dword]: rows 8g+4*l5 + {0,1},{2,3}
#pragma unroll
    for (int g = 0; g < 4; ++g) {
      pkd0[g][0] = cvt_pk_bf16(__expf(s0[4 * g + 0]), __expf(s0[4 * g + 1]));
      pkd0[g][1] = cvt_pk_bf16(__expf(s0[4 * g + 2]), __expf(s0[4 * g + 3]));
      pkd1[g][0] = cvt_pk_bf16(__expf(s1[4 * g + 0]), __expf(s1[4 * g + 1]));
      pkd1[g][1] = cvt_pk_bf16(__expf(s1[4 * g + 2]), __expf(s1[4 * g + 3]));
    }

    // ---- late V wait: drain exactly through V(kt) ----
    if (kt < 14)      { asm volatile("s_waitcnt vmcnt(4)" ::: "memory"); }
    else if (kt < 15) { asm volatile("s_waitcnt vmcnt(2)" ::: "memory"); }
    else              { asm volatile("s_waitcnt vmcnt(0)" ::: "memory"); }
    __builtin_amdgcn_sched_barrier(0);

    // ---- O^T += V^T . P^T ;  ol += ones . P^T (lsum on the MFMA pipe) ----
    __builtin_amdgcn_s_setprio(1);
#pragma unroll
    for (int ks = 0; ks < 4; ++ks) {
      const int gA = (2 * ks) & 3, gB = (2 * ks + 1) & 3;
      unsigned a0, a1, b0, b1;
      if (ks < 2) { a0 = pkd0[gA][0]; a1 = pkd0[gA][1]; b0 = pkd0[gB][0]; b1 = pkd0[gB][1]; }
      else        { a0 = pkd1[gA][0]; a1 = pkd1[gA][1]; b0 = pkd1[gB][0]; b1 = pkd1[gB][1]; }
      union { unsigned d[4]; bf16x8 v; } pf;
#if __has_builtin(__builtin_amdgcn_permlane32_swap)
      {
        auto r0 = __builtin_amdgcn_permlane32_swap(a0, b0, false, false);
        auto r1 = __builtin_amdgcn_permlane32_swap(a1, b1, false, false);
        pf.d[0] = r0[0]; pf.d[1] = r1[0]; pf.d[2] = r0[1]; pf.d[3] = r1[1];
      }
#else
      {
        const unsigned long long A = (unsigned long long)a0 | ((unsigned long long)a1 << 32);
        const unsigned long long B = (unsigned long long)b0 | ((unsigned long long)b1 << 32);
        const unsigned long long own = l5 ? B : A;
        const unsigned long long send = l5 ? A : B;
        const unsigned long long recv = __shfl_xor(send, 32);
        const unsigned long long w0 = l5 ? recv : own;
        const unsigned long long w1 = l5 ? own : recv;
        pf.d[0] = (unsigned)w0; pf.d[1] = (unsigned)(w0 >> 32);
        pf.d[2] = (unsigned)w1; pf.d[3] = (unsigned)(w1 >> 32);
      }
#endif
      ol = MFMA_32x32x16(onesf, pf.v, ol);
      {
        const int u = (ks * 2 + l5) ^ (l31 & 7);
        const bf16x8 vf = *(const bf16x8*)(&Vb[vs][l31 * 64 + u * 8]);
        o0 = MFMA_32x32x16(vf, pf.v, o0);
      }
      {
        const int row = 32 + l31;
        const int u = (ks * 2 + l5) ^ (row & 7);
        const bf16x8 vf = *(const bf16x8*)(&Vb[vs][row * 64 + u * 8]);
        o1 = MFMA_32x32x16(vf, pf.v, o1);
      }
    }
    __builtin_amdgcn_s_setprio(0);

    if (kt < 15) {
      __builtin_amdgcn_s_barrier();
      __builtin_amdgcn_sched_barrier(0);
    }
  }

  // ---- epilogue: store unnormalized partial O (bf16) + row-sum ----
  const float lsum = ol[0];  // ol[r] = lsum[q=l31] for all r; covers both halves
  const size_t pbase = ((size_t)(bh * 16 + qtt) * 2 + sg) * 8192;
  const int ql = wid * 32 + l31;
  short* pg = (short*)partb;
#pragma unroll
  for (int mt = 0; mt < 2; ++mt) {
    const f32x16& o = mt ? o1 : o0;
#pragma unroll
    for (int rg = 0; rg < 4; ++rg) {
      const int d0 = 32 * mt + 8 * rg + 4 * l5;
      bf16x4v w;
#pragma unroll
      for (int el = 0; el < 4; ++el) w[el] = f2bf(o[4 * rg + el]);
      *(bf16x4v*)(pg + pbase + (size_t)ql * 64 + d0) = w;
    }
  }
  if (l5 == 0) {
    const size_t sb = ((size_t)(bh * 16 + qtt) * 2 + sg) * 128;
    stats[sb + ql] = lsum;
  }
}

// ---------- merge the two KV-splits -> final O (bf16), 16B accesses ----------
__global__ __launch_bounds__(256) void merge_kernel(const __hip_bfloat16* __restrict__ partb,
                                                    const float* __restrict__ stats,
                                                    __hip_bfloat16* __restrict__ O) {
  const int bid = blockIdx.x;
  const int qtt = bid & 15, bh = bid >> 4;
  const int h = bh & 15, b = bh >> 4;
  const int tid = threadIdx.x;
  const int r = tid >> 1, dh = (tid & 1) * 32;
  const size_t base = (size_t)(bh * 16 + qtt) * 2;
  const size_t p0 = base * 8192, p1 = p0 + 8192;
  const float l0 = stats[base * 128 + r], l1 = stats[base * 128 + 128 + r];
  const float inv = 1.0f / (l0 + l1);
  const short* pg = (const short*)partb;
  short* Og = (short*)O;
  const size_t orow = ((size_t)b * 2048 + qtt * 128 + r) * 1024 + h * 64 + dh;
#pragma unroll
  for (int j = 0; j < 4; ++j) {
    bf16x8 a = *(const bf16x8*)(pg + p0 + (size_t)r * 64 + dh + 8 * j);
    bf16x8 c = *(const bf16x8*)(pg + p1 + (size_t)r * 64 + dh + 8 * j);
    bf16x8 o;
#pragma unroll
    for (int el = 0; el < 8; ++el) o[el] = f2bf((bf2f(a[el]) + bf2f(c[el])) * inv);
    *(bf16x8*)(Og + orow + 8 * j) = o;
  }
}

extern "C" void kernel_launch(void* const* d_in, const int* in_sizes, int n_in,
                              void* d_out, int out_size, void* d_ws, size_t ws_size,
                              hipStream_t stream) {
  const float* x = (const float*)d_in[0];
  const float* Wq = (const float*)d_in[1];
  const float* Wk = (const float*)d_in[2];
  const float* Wv = (const float*)d_in[3];
  const float* Wo = (const float*)d_in[4];
  float* out = (float*)d_out;

  __hip_bfloat16* ws = (__hip_bfloat16*)d_ws;
  const size_t MT = (size_t)4096 * 1024;
  const size_t WT = (size_t)1024 * 1024;
  __hip_bfloat16* xb = ws;             // x bf16 (dead after QKV gemm)
  __hip_bfloat16* wall = ws + MT;      // [Wo][Wq][Wk][Wv] bf16
  __hip_bfloat16* wob = wall;
  __hip_bfloat16* wqkv = wall + WT;    // Wq|Wk|Wv contiguous (3072 rows)
  __hip_bfloat16* qkvb = wall + 4 * WT;              // [4096, 3072] (V third unused)
  __hip_bfloat16* vtb = qkvb + (size_t)4096 * 3072;  // [2,16,64,2048]; later final O
  __hip_bfloat16* partb = vtb + MT;                  // partial O, 8M bf16 (16MB)
  float* stats = (float*)wqkv;         // 512KB, overlays dead Wq-bf16 during attn

  cast_all<<<2048, 256, 0, stream>>>(x, Wq, Wk, Wv, Wo, xb, wall);

  // fused QKV projection, 64x128 tiles (1536 blocks = 6/CU): Q|K into qkvb,
  // V written directly transposed (coalesced via LDS bounce) into vtb.
  gemm_bt<2, 0, 1><<<1536, 256, 0, stream>>>(xb, wqkv, qkvb, 3072, 24, vtb);

  attn_kernel<<<1024, 256, 0, stream>>>(qkvb, vtb, partb, stats);

  merge_kernel<<<512, 256, 0, stream>>>(partb, stats, vtb);  // final O -> vtb region

  // output projection, 32x128 tiles (1024 blocks = 4/CU)
  gemm_bt<1, 1, 0><<<1024, 256, 0, stream>>>(vtb, wob, out, 1024, 8, nullptr);
}